// Round 5
// baseline (401.926 us; speedup 1.0000x reference)
//
#include <hip/hip_runtime.h>
#include <hip/hip_bf16.h>
#include <cstdint>
#include <cstddef>

// AxialAttentionModule round 5:
//  - attn_row: LDS 55.3->46.1 KB (3 blocks/CU), mask removed from hot path
//    (block-uniform need_mask guard), defer-max (THR=5), setprio around MFMA.
//  - out-projs write bf16 r/c buffers; LN does src + r + c (acc eliminated).
//  - single qkv buffer reused by col path (stream-ordered).
// Fixed shapes: N=512 D=32 B=4 E=256 H=4 HD=64.

typedef __hip_bfloat16 bf16;
typedef __attribute__((ext_vector_type(8))) short bf16x8;
typedef __attribute__((ext_vector_type(8))) short short8;
typedef __attribute__((ext_vector_type(4))) short bf16x4;
typedef __attribute__((ext_vector_type(4))) float f32x4;

#define NN 512
#define DD 32
#define BB 4
#define EE 256
#define HH 4
#define HDIM 64
#define DB (DD*BB)        // 128
#define MTOK (NN*DD*BB)   // 65536
#define QKV3 (3*EE)       // 768
#define KBLK 64

__device__ __forceinline__ float bf2f(bf16 x){ return __bfloat162float(x); }
__device__ __forceinline__ bf16 f2bf(float x){ return __float2bfloat16(x); }

#define AS1C(p) ((const __attribute__((address_space(1))) void*)(p))
#define AS3(p)  ((__attribute__((address_space(3))) void*)(p))

// ---------------------------------------------------------------------------
// fp32 -> bf16 bulk convert
// ---------------------------------------------------------------------------
__global__ __launch_bounds__(256) void cvt_kernel(
    const float* __restrict__ in, bf16* __restrict__ out, int n)
{
  int i = (blockIdx.x * 256 + threadIdx.x) * 8;
  if (i >= n) return;
  const float* p = in + i;
  short8 o;
  #pragma unroll
  for (int j = 0; j < 8; ++j)
    ((bf16*)&o)[j] = f2bf(p[j]);
  *(short8*)(out + i) = o;
}

// ---------------------------------------------------------------------------
// MFMA GEMM: C[M, NOUT] = A[M,256] @ W[NOUT,256]^T + bias, bf16 out.
// 128x128 tile, BK=64, 4 waves. XOR-swizzled LDS (pre-swizzled global src).
// 1-D grid 512*NT with per-XCD m-chunking.
// ---------------------------------------------------------------------------
template<int NT, int NOUT>
__global__ __launch_bounds__(256,2) void gemm_mfma(
    const bf16* __restrict__ A, const bf16* __restrict__ W,
    const float* __restrict__ bias, bf16* __restrict__ C)
{
  __shared__ bf16 As[128][64];
  __shared__ bf16 Bs[128][64];
  const int bid = blockIdx.x;
  const int xcd = bid & 7;
  const int i0  = bid >> 3;
  const int bm  = xcd * 64 + i0 / NT;
  const int bn  = i0 % NT;

  const int tid  = threadIdx.x;
  const int wid  = tid >> 6;
  const int lane = tid & 63;
  const int lo = lane & 15, hi = lane >> 4;
  const int wr = wid >> 1, wc = wid & 1;

  const int srow = lane >> 3;
  const int slin = (lane & 7) << 4;
  const int ssrc = slin ^ (srow << 4);

  f32x4 acc[4][4] = {};

  for (int k0 = 0; k0 < 256; k0 += 64) {
    __syncthreads();
    #pragma unroll
    for (int i = 0; i < 4; ++i) {
      const int r = wid * 32 + i * 8 + srow;
      const int m = bm * 128 + r;
      const char* gpA = (const char*)(A + (size_t)m * EE + k0) + ssrc;
      __builtin_amdgcn_global_load_lds(AS1C(gpA), AS3(&As[wid*32 + i*8][0]), 16, 0, 0);
      const int wn = bn * 128 + r;
      const char* gpB = (const char*)(W + (size_t)wn * EE + k0) + ssrc;
      __builtin_amdgcn_global_load_lds(AS1C(gpB), AS3(&Bs[wid*32 + i*8][0]), 16, 0, 0);
    }
    __syncthreads();

    #pragma unroll
    for (int kc = 0; kc < 2; ++kc) {
      const int cc = kc * 64 + hi * 16;
      bf16x8 af[4], bfr[4];
      #pragma unroll
      for (int i = 0; i < 4; ++i) {
        const int ra = wr * 64 + i * 16 + lo;
        af[i]  = *(const bf16x8*)((const char*)&As[ra][0] + (cc ^ ((ra & 7) << 4)));
        const int rb = wc * 64 + i * 16 + lo;
        bfr[i] = *(const bf16x8*)((const char*)&Bs[rb][0] + (cc ^ ((rb & 7) << 4)));
      }
      __builtin_amdgcn_s_setprio(1);
      #pragma unroll
      for (int mi = 0; mi < 4; ++mi)
        #pragma unroll
        for (int ni = 0; ni < 4; ++ni)
          acc[mi][ni] = __builtin_amdgcn_mfma_f32_16x16x32_bf16(
              af[mi], bfr[ni], acc[mi][ni], 0, 0, 0);
      __builtin_amdgcn_s_setprio(0);
    }
  }

  float bv[4];
  #pragma unroll
  for (int ni = 0; ni < 4; ++ni)
    bv[ni] = bias[bn * 128 + wc * 64 + ni * 16 + lo];

  #pragma unroll
  for (int mi = 0; mi < 4; ++mi) {
    #pragma unroll
    for (int r = 0; r < 4; ++r) {
      const int m = bm * 128 + wr * 64 + mi * 16 + hi * 4 + r;
      #pragma unroll
      for (int ni = 0; ni < 4; ++ni) {
        const int col = bn * 128 + wc * 64 + ni * 16 + lo;
        C[(size_t)m * NOUT + col] = f2bf(acc[mi][ni][r] + bv[ni]);
      }
    }
  }
}

// ---------------------------------------------------------------------------
// Row attention, MFMA flash, QBLK=128, 3 blocks/CU.
// ---------------------------------------------------------------------------
__global__ __launch_bounds__(256) void attn_row_mfma(
    const bf16* __restrict__ qkv, bf16* __restrict__ attn,
    const int* __restrict__ sep_ptr)
{
  const int bid = blockIdx.x;
  const int xcd = bid & 7;
  const int idx = bid >> 3;
  const int pair = xcd * 64 + (idx >> 2);
  const int qt = idx & 3;
  const int t = pair >> 2;
  const int h = pair & 3;
  const int sep = *sep_ptr;

  const int tid  = threadIdx.x;
  const int wid  = tid >> 6;
  const int lane = tid & 63;
  const int lo = lane & 15, hi = lane >> 4;

  __shared__ bf16 Ks[2][KBLK][72];
  __shared__ bf16 Vt[2][HDIM][72];
  __shared__ bf16 Ps[4][16][72];

  const int qb = qt * 128;
  const int q0 = qb + wid * 32;

  bf16x8 qf[2][2];
  #pragma unroll
  for (int mf = 0; mf < 2; ++mf) {
    const bf16* Qp = qkv + ((size_t)(q0 + mf*16 + lo) * DB + t) * QKV3 + h * HDIM;
    qf[mf][0] = *(const bf16x8*)(Qp + hi * 8);
    qf[mf][1] = *(const bf16x8*)(Qp + 32 + hi * 8);
  }

  const int kr  = tid >> 2;
  const int kc4 = (tid & 3) * 16;
  const int vr  = tid & 63;
  const int vc  = (tid >> 6) * 16;
  const bf16* Kbase = qkv + ((size_t)kr * DB + t) * QKV3 + EE + h * HDIM + kc4;
  const bf16* Vbase = qkv + ((size_t)vr * DB + t) * QKV3 + 2*EE + h * HDIM + vc;
  const size_t kstep = (size_t)KBLK * DB * QKV3;

  f32x4 Oa[2][4] = {};
  float m_run[2][4], l_run[2][4];
  #pragma unroll
  for (int mf = 0; mf < 2; ++mf)
    #pragma unroll
    for (int r = 0; r < 4; ++r) { m_run[mf][r] = -1e30f; l_run[mf][r] = 0.f; }

  const int nkt = (qb >= sep) ? ((sep + KBLK - 1) >> 6) : (NN >> 6);
  const bool need_mask = (qb + 128 > sep) && (nkt * KBLK > sep);

  bf16x8 kg0 = *(const bf16x8*)(Kbase);
  bf16x8 kg1 = *(const bf16x8*)(Kbase + 8);
  bf16x8 vg0 = *(const bf16x8*)(Vbase);
  bf16x8 vg1 = *(const bf16x8*)(Vbase + 8);

  for (int kt = 0; kt < nkt; ++kt) {
    const int k0 = kt * KBLK;
    const int p = kt & 1;

    *(bf16x8*)&Ks[p][kr][kc4]     = kg0;
    *(bf16x8*)&Ks[p][kr][kc4 + 8] = kg1;
    #pragma unroll
    for (int j = 0; j < 8; ++j) {
      Vt[p][vc + j][vr]     = ((const bf16*)&vg0)[j];
      Vt[p][vc + 8 + j][vr] = ((const bf16*)&vg1)[j];
    }
    __syncthreads();

    if (kt + 1 < nkt) {
      const size_t off = (size_t)(kt + 1) * kstep;
      kg0 = *(const bf16x8*)(Kbase + off);
      kg1 = *(const bf16x8*)(Kbase + off + 8);
      vg0 = *(const bf16x8*)(Vbase + off);
      vg1 = *(const bf16x8*)(Vbase + off + 8);
    }

    // ---- QK^T ----
    f32x4 sc[2][4];
    {
      bf16x8 kf[4][2];
      #pragma unroll
      for (int kb = 0; kb < 4; ++kb)
        #pragma unroll
        for (int kc = 0; kc < 2; ++kc)
          kf[kb][kc] = *(const bf16x8*)&Ks[p][kb*16 + lo][kc*32 + hi*8];
      __builtin_amdgcn_s_setprio(1);
      #pragma unroll
      for (int kb = 0; kb < 4; ++kb) {
        sc[0][kb] = (f32x4){0,0,0,0};
        sc[1][kb] = (f32x4){0,0,0,0};
        #pragma unroll
        for (int kc = 0; kc < 2; ++kc) {
          sc[0][kb] = __builtin_amdgcn_mfma_f32_16x16x32_bf16(qf[0][kc], kf[kb][kc], sc[0][kb], 0, 0, 0);
          sc[1][kb] = __builtin_amdgcn_mfma_f32_16x16x32_bf16(qf[1][kc], kf[kb][kc], sc[1][kb], 0, 0, 0);
        }
      }
      __builtin_amdgcn_s_setprio(0);
    }

    // ---- softmax + PV per 16-row frag ----
    #pragma unroll
    for (int mf = 0; mf < 2; ++mf) {
      float tmax[4] = {-1e30f,-1e30f,-1e30f,-1e30f};
      #pragma unroll
      for (int kb = 0; kb < 4; ++kb) {
        #pragma unroll
        for (int r = 0; r < 4; ++r) {
          const float sv = sc[mf][kb][r] * 0.125f;
          sc[mf][kb][r] = sv;
          tmax[r] = fmaxf(tmax[r], sv);
        }
      }
      if (need_mask && k0 + KBLK > sep) {   // block-uniform, cold path
        #pragma unroll
        for (int kb = 0; kb < 4; ++kb) {
          const int kk = k0 + kb*16 + lo;
          #pragma unroll
          for (int r = 0; r < 4; ++r) {
            const int qq = q0 + mf*16 + hi*4 + r;
            if (qq >= sep && kk >= sep) sc[mf][kb][r] = -1e30f;
          }
        }
        #pragma unroll
        for (int r = 0; r < 4; ++r) {
          tmax[r] = -1e30f;
          #pragma unroll
          for (int kb = 0; kb < 4; ++kb) tmax[r] = fmaxf(tmax[r], sc[mf][kb][r]);
        }
      }
      #pragma unroll
      for (int r = 0; r < 4; ++r) {
        #pragma unroll
        for (int off = 1; off < 16; off <<= 1)
          tmax[r] = fmaxf(tmax[r], __shfl_xor(tmax[r], off));
      }
      // defer-max: skip rescale when max barely grew
      float needv = -1e30f;
      #pragma unroll
      for (int r = 0; r < 4; ++r) needv = fmaxf(needv, tmax[r] - m_run[mf][r]);
      if (__any(needv > 5.f)) {
        #pragma unroll
        for (int r = 0; r < 4; ++r) {
          const float mn = fmaxf(m_run[mf][r], tmax[r]);
          const float corr = __expf(m_run[mf][r] - mn);
          m_run[mf][r] = mn;
          l_run[mf][r] *= corr;
          #pragma unroll
          for (int n = 0; n < 4; ++n) Oa[mf][n][r] *= corr;
        }
      }
      float psum[4];
      #pragma unroll
      for (int r = 0; r < 4; ++r) {
        float s0 = 0.f;
        #pragma unroll
        for (int kb = 0; kb < 4; ++kb) {
          const float pv = __expf(sc[mf][kb][r] - m_run[mf][r]);
          sc[mf][kb][r] = pv;
          s0 += pv;
        }
        psum[r] = s0;
      }
      #pragma unroll
      for (int r = 0; r < 4; ++r) {
        #pragma unroll
        for (int off = 1; off < 16; off <<= 1)
          psum[r] += __shfl_xor(psum[r], off);
        l_run[mf][r] += psum[r];
      }

      // P -> LDS relayout (per-wave, 16 rows)
      #pragma unroll
      for (int kb = 0; kb < 4; ++kb)
        #pragma unroll
        for (int r = 0; r < 4; ++r)
          Ps[wid][hi*4 + r][kb*16 + lo] = f2bf(sc[mf][kb][r]);

      bf16x8 pa[2];
      #pragma unroll
      for (int kc = 0; kc < 2; ++kc)
        pa[kc] = *(const bf16x8*)&Ps[wid][lo][kc*32 + hi*8];
      __builtin_amdgcn_s_setprio(1);
      #pragma unroll
      for (int n = 0; n < 4; ++n) {
        #pragma unroll
        for (int kc = 0; kc < 2; ++kc) {
          bf16x8 vf = *(const bf16x8*)&Vt[p][n*16 + lo][kc*32 + hi*8];
          Oa[mf][n] = __builtin_amdgcn_mfma_f32_16x16x32_bf16(pa[kc], vf, Oa[mf][n], 0, 0, 0);
        }
      }
      __builtin_amdgcn_s_setprio(0);
    }
  }

  #pragma unroll
  for (int mf = 0; mf < 2; ++mf) {
    #pragma unroll
    for (int r = 0; r < 4; ++r) {
      const float inv = 1.f / l_run[mf][r];
      const int qq = q0 + mf*16 + hi*4 + r;
      bf16* Op = attn + ((size_t)qq * DB + t) * EE + h * HDIM;
      #pragma unroll
      for (int n = 0; n < 4; ++n)
        Op[n*16 + lo] = f2bf(Oa[mf][n][r] * inv);
    }
  }
}

// ---------------------------------------------------------------------------
// Col attention: block per (n,b,h); S=32 over D axis, no mask. Row-token qkv.
// ---------------------------------------------------------------------------
__global__ __launch_bounds__(256) void attn_col_kernel(
    const bf16* __restrict__ qkv, bf16* __restrict__ attn)
{
  const int bid = blockIdx.x;
  const int n = bid >> 4;
  const int b = (bid >> 2) & 3;
  const int h = bid & 3;
  const int tid = threadIdx.x;

  __shared__ float Qs[DD*65], Kx[DD*65], Vs[DD*65];
  __shared__ float P[DD*33];

  {
    const int d = tid >> 3, c = (tid & 7) * 8;
    const size_t base = ((size_t)(n*DB + d*BB + b)) * QKV3 + h*HDIM + c;
    bf16x8 qv = *(const bf16x8*)(qkv + base);
    bf16x8 kv = *(const bf16x8*)(qkv + base + EE);
    bf16x8 vv = *(const bf16x8*)(qkv + base + 2*EE);
    #pragma unroll
    for (int j = 0; j < 8; ++j) {
      Qs[d*65 + c + j] = bf2f(((const bf16*)&qv)[j]);
      Kx[d*65 + c + j] = bf2f(((const bf16*)&kv)[j]);
      Vs[d*65 + c + j] = bf2f(((const bf16*)&vv)[j]);
    }
  }
  __syncthreads();

  const int qi = tid >> 3, kg = tid & 7;
  {
    float s[4] = {0.f, 0.f, 0.f, 0.f};
    for (int e = 0; e < HDIM; ++e) {
      const float qv = Qs[qi*65 + e];
      #pragma unroll
      for (int j = 0; j < 4; ++j)
        s[j] += qv * Kx[(kg*4 + j)*65 + e];
    }
    float mx = -1e30f;
    #pragma unroll
    for (int j = 0; j < 4; ++j) { s[j] *= 0.125f; mx = fmaxf(mx, s[j]); }
    #pragma unroll
    for (int off = 1; off < 8; off <<= 1)
      mx = fmaxf(mx, __shfl_xor(mx, off));
    float sum = 0.f;
    #pragma unroll
    for (int j = 0; j < 4; ++j) { s[j] = __expf(s[j] - mx); sum += s[j]; }
    #pragma unroll
    for (int off = 1; off < 8; off <<= 1)
      sum += __shfl_xor(sum, off);
    const float inv = 1.f / sum;
    #pragma unroll
    for (int j = 0; j < 4; ++j)
      P[qi*33 + kg*4 + j] = s[j] * inv;
  }
  __syncthreads();

  {
    const int eb = (tid & 7) * 8;
    float acc[8] = {};
    for (int ki = 0; ki < DD; ++ki) {
      const float pv = P[qi*33 + ki];
      #pragma unroll
      for (int j = 0; j < 8; ++j)
        acc[j] += pv * Vs[ki*65 + eb + j];
    }
    bf16x8 o;
    #pragma unroll
    for (int j = 0; j < 8; ++j)
      ((bf16*)&o)[j] = f2bf(acc[j]);
    *(bf16x8*)(attn + ((size_t)(n*DB + qi*BB + b)) * EE + h*HDIM + eb) = o;
  }
}

// ---------------------------------------------------------------------------
// Final: out = LayerNorm(src + r + c).  4 tokens/block, shuffle reduce.
// ---------------------------------------------------------------------------
__global__ __launch_bounds__(256) void ln_kernel(
    const float* __restrict__ src, const bf16* __restrict__ rp,
    const bf16* __restrict__ cp, const float* __restrict__ g,
    const float* __restrict__ b, float* __restrict__ out)
{
  const int m = blockIdx.x * 4 + (threadIdx.x >> 6);
  const int lane = threadIdx.x & 63;
  const float4 s4 = ((const float4*)src)[(size_t)m*64 + lane];
  const bf16x4 r4 = ((const bf16x4*)rp)[(size_t)m*64 + lane];
  const bf16x4 c4 = ((const bf16x4*)cp)[(size_t)m*64 + lane];
  float4 x;
  x.x = s4.x + bf2f(((const bf16*)&r4)[0]) + bf2f(((const bf16*)&c4)[0]);
  x.y = s4.y + bf2f(((const bf16*)&r4)[1]) + bf2f(((const bf16*)&c4)[1]);
  x.z = s4.z + bf2f(((const bf16*)&r4)[2]) + bf2f(((const bf16*)&c4)[2]);
  x.w = s4.w + bf2f(((const bf16*)&r4)[3]) + bf2f(((const bf16*)&c4)[3]);
  float sum = x.x + x.y + x.z + x.w;
  #pragma unroll
  for (int off = 1; off < 64; off <<= 1) sum += __shfl_xor(sum, off);
  const float mu = sum * (1.f/EE);
  float4 d;
  d.x = x.x - mu; d.y = x.y - mu; d.z = x.z - mu; d.w = x.w - mu;
  float ss = d.x*d.x + d.y*d.y + d.z*d.z + d.w*d.w;
  #pragma unroll
  for (int off = 1; off < 64; off <<= 1) ss += __shfl_xor(ss, off);
  const float rstd = rsqrtf(ss * (1.f/EE) + 1e-5f);
  const float4 g4 = ((const float4*)g)[lane];
  const float4 b4 = ((const float4*)b)[lane];
  float4 o;
  o.x = d.x * rstd * g4.x + b4.x;
  o.y = d.y * rstd * g4.y + b4.y;
  o.z = d.z * rstd * g4.z + b4.z;
  o.w = d.w * rstd * g4.w + b4.w;
  ((float4*)out)[(size_t)m*64 + lane] = o;
}

// ---------------------------------------------------------------------------
extern "C" void kernel_launch(void* const* d_in, const int* in_sizes, int n_in,
                              void* d_out, int out_size, void* d_ws, size_t ws_size,
                              hipStream_t stream)
{
  const float* src      = (const float*)d_in[0];
  const float* w_in_row = (const float*)d_in[1];
  const float* b_in_row = (const float*)d_in[2];
  const float* w_out_row= (const float*)d_in[3];
  const float* b_out_row= (const float*)d_in[4];
  const float* w_in_col = (const float*)d_in[5];
  const float* b_in_col = (const float*)d_in[6];
  const float* w_out_col= (const float*)d_in[7];
  const float* b_out_col= (const float*)d_in[8];
  const float* ln_g     = (const float*)d_in[9];
  const float* ln_b     = (const float*)d_in[10];
  const int*   sep_ptr  = (const int*)d_in[12];
  float* out = (float*)d_out;

  char* ws = (char*)d_ws;
  bf16*  qkv    = (bf16*)(ws);                       // 100663296
  bf16*  attnX  = (bf16*)(ws + 100663296);           //  33554432
  bf16*  r_out  = (bf16*)(ws + 134217728);           //  33554432
  bf16*  c_out  = (bf16*)(ws + 167772160);           //  33554432
  bf16*  src_bf = (bf16*)(ws + 201326592);           //  33554432
  bf16*  wbf_ir = (bf16*)(ws + 234881024);
  bf16*  wbf_or = (bf16*)(ws + 235274240);
  bf16*  wbf_ic = (bf16*)(ws + 235405312);
  bf16*  wbf_oc = (bf16*)(ws + 235798528);

  dim3 blk(256);

  // converts
  cvt_kernel<<<dim3(MTOK*EE/8/256), blk, 0, stream>>>(src, src_bf, MTOK*EE);
  cvt_kernel<<<dim3(QKV3*EE/8/256), blk, 0, stream>>>(w_in_row, wbf_ir, QKV3*EE);
  cvt_kernel<<<dim3(EE*EE/8/256),   blk, 0, stream>>>(w_out_row, wbf_or, EE*EE);
  cvt_kernel<<<dim3(QKV3*EE/8/256), blk, 0, stream>>>(w_in_col, wbf_ic, QKV3*EE);
  cvt_kernel<<<dim3(EE*EE/8/256),   blk, 0, stream>>>(w_out_col, wbf_oc, EE*EE);

  // row path
  gemm_mfma<6,QKV3><<<dim3(512*6), blk, 0, stream>>>(src_bf, wbf_ir, b_in_row, qkv);
  attn_row_mfma<<<dim3(2048), blk, 0, stream>>>(qkv, attnX, sep_ptr);
  gemm_mfma<2,EE><<<dim3(512*2), blk, 0, stream>>>(attnX, wbf_or, b_out_row, r_out);

  // col path (qkv + attnX buffers reused, stream-ordered)
  gemm_mfma<6,QKV3><<<dim3(512*6), blk, 0, stream>>>(src_bf, wbf_ic, b_in_col, qkv);
  attn_col_kernel<<<dim3(NN*BB*HH), blk, 0, stream>>>(qkv, attnX);
  gemm_mfma<2,EE><<<dim3(512*2), blk, 0, stream>>>(attnX, wbf_oc, b_out_col, c_out);

  // residual + LayerNorm
  ln_kernel<<<dim3(MTOK/4), blk, 0, stream>>>(src, r_out, c_out, ln_g, ln_b, out);
}

// Round 6
// 340.850 us; speedup vs baseline: 1.1792x; 1.1792x over previous
//
#include <hip/hip_runtime.h>
#include <hip/hip_bf16.h>
#include <cstdint>
#include <cstddef>

// AxialAttentionModule round 6:
//  - attn_row rewritten: swapped QK^T (S^T = K x Q) -> softmax fully
//    in-register (2 shuffles), P->PV via in-lane repack + permuted-k V reads
//    (no Ps LDS round-trip). LDS 36.9KB -> 4 blocks/CU. Grid 4096.
//  - ln reads bf16 src; weight cvts merged into one launch.
// Fixed shapes: N=512 D=32 B=4 E=256 H=4 HD=64.

typedef __hip_bfloat16 bf16;
typedef __attribute__((ext_vector_type(8))) short bf16x8;
typedef __attribute__((ext_vector_type(8))) short short8;
typedef __attribute__((ext_vector_type(4))) short bf16x4;
typedef __attribute__((ext_vector_type(4))) float f32x4;

#define NN 512
#define DD 32
#define BB 4
#define EE 256
#define HH 4
#define HDIM 64
#define DB (DD*BB)        // 128
#define MTOK (NN*DD*BB)   // 65536
#define QKV3 (3*EE)       // 768
#define KBLK 64

__device__ __forceinline__ float bf2f(bf16 x){ return __bfloat162float(x); }
__device__ __forceinline__ bf16 f2bf(float x){ return __float2bfloat16(x); }

#define AS1C(p) ((const __attribute__((address_space(1))) void*)(p))
#define AS3(p)  ((__attribute__((address_space(3))) void*)(p))

// ---------------------------------------------------------------------------
// fp32 -> bf16 bulk convert (src)
// ---------------------------------------------------------------------------
__global__ __launch_bounds__(256) void cvt_kernel(
    const float* __restrict__ in, bf16* __restrict__ out, int n)
{
  int i = (blockIdx.x * 256 + threadIdx.x) * 8;
  if (i >= n) return;
  const float* p = in + i;
  short8 o;
  #pragma unroll
  for (int j = 0; j < 8; ++j)
    ((bf16*)&o)[j] = f2bf(p[j]);
  *(short8*)(out + i) = o;
}

// ---------------------------------------------------------------------------
// all 4 weight converts in one launch. 2048 elems/block, 256 blocks.
// ---------------------------------------------------------------------------
__global__ __launch_bounds__(256) void cvt_w_kernel(
    const float* __restrict__ ir, const float* __restrict__ orr,
    const float* __restrict__ ic, const float* __restrict__ oc,
    bf16* __restrict__ d_ir, bf16* __restrict__ d_or,
    bf16* __restrict__ d_ic, bf16* __restrict__ d_oc)
{
  const int b = blockIdx.x;
  const float* src; bf16* dst; int off;
  if (b < 96)       { src = ir;  dst = d_ir; off = b; }
  else if (b < 128) { src = orr; dst = d_or; off = b - 96; }
  else if (b < 224) { src = ic;  dst = d_ic; off = b - 128; }
  else              { src = oc;  dst = d_oc; off = b - 224; }
  const int i = (off * 256 + threadIdx.x) * 8;
  const float* p = src + i;
  short8 o;
  #pragma unroll
  for (int j = 0; j < 8; ++j)
    ((bf16*)&o)[j] = f2bf(p[j]);
  *(short8*)(dst + i) = o;
}

// ---------------------------------------------------------------------------
// MFMA GEMM (unchanged): C[M, NOUT] = A[M,256] @ W[NOUT,256]^T + bias.
// ---------------------------------------------------------------------------
template<int NT, int NOUT>
__global__ __launch_bounds__(256,2) void gemm_mfma(
    const bf16* __restrict__ A, const bf16* __restrict__ W,
    const float* __restrict__ bias, bf16* __restrict__ C)
{
  __shared__ bf16 As[128][64];
  __shared__ bf16 Bs[128][64];
  const int bid = blockIdx.x;
  const int xcd = bid & 7;
  const int i0  = bid >> 3;
  const int bm  = xcd * 64 + i0 / NT;
  const int bn  = i0 % NT;

  const int tid  = threadIdx.x;
  const int wid  = tid >> 6;
  const int lane = tid & 63;
  const int lo = lane & 15, hi = lane >> 4;
  const int wr = wid >> 1, wc = wid & 1;

  const int srow = lane >> 3;
  const int slin = (lane & 7) << 4;
  const int ssrc = slin ^ (srow << 4);

  f32x4 acc[4][4] = {};

  for (int k0 = 0; k0 < 256; k0 += 64) {
    __syncthreads();
    #pragma unroll
    for (int i = 0; i < 4; ++i) {
      const int r = wid * 32 + i * 8 + srow;
      const int m = bm * 128 + r;
      const char* gpA = (const char*)(A + (size_t)m * EE + k0) + ssrc;
      __builtin_amdgcn_global_load_lds(AS1C(gpA), AS3(&As[wid*32 + i*8][0]), 16, 0, 0);
      const int wn = bn * 128 + r;
      const char* gpB = (const char*)(W + (size_t)wn * EE + k0) + ssrc;
      __builtin_amdgcn_global_load_lds(AS1C(gpB), AS3(&Bs[wid*32 + i*8][0]), 16, 0, 0);
    }
    __syncthreads();

    #pragma unroll
    for (int kc = 0; kc < 2; ++kc) {
      const int cc = kc * 64 + hi * 16;
      bf16x8 af[4], bfr[4];
      #pragma unroll
      for (int i = 0; i < 4; ++i) {
        const int ra = wr * 64 + i * 16 + lo;
        af[i]  = *(const bf16x8*)((const char*)&As[ra][0] + (cc ^ ((ra & 7) << 4)));
        const int rb = wc * 64 + i * 16 + lo;
        bfr[i] = *(const bf16x8*)((const char*)&Bs[rb][0] + (cc ^ ((rb & 7) << 4)));
      }
      __builtin_amdgcn_s_setprio(1);
      #pragma unroll
      for (int mi = 0; mi < 4; ++mi)
        #pragma unroll
        for (int ni = 0; ni < 4; ++ni)
          acc[mi][ni] = __builtin_amdgcn_mfma_f32_16x16x32_bf16(
              af[mi], bfr[ni], acc[mi][ni], 0, 0, 0);
      __builtin_amdgcn_s_setprio(0);
    }
  }

  float bv[4];
  #pragma unroll
  for (int ni = 0; ni < 4; ++ni)
    bv[ni] = bias[bn * 128 + wc * 64 + ni * 16 + lo];

  #pragma unroll
  for (int mi = 0; mi < 4; ++mi) {
    #pragma unroll
    for (int r = 0; r < 4; ++r) {
      const int m = bm * 128 + wr * 64 + mi * 16 + hi * 4 + r;
      #pragma unroll
      for (int ni = 0; ni < 4; ++ni) {
        const int col = bn * 128 + wc * 64 + ni * 16 + lo;
        C[(size_t)m * NOUT + col] = f2bf(acc[mi][ni][r] + bv[ni]);
      }
    }
  }
}

// ---------------------------------------------------------------------------
// Row attention v3: swapped QK^T, in-register softmax, permuted-k PV.
// Grid 4096: xcd=bid&7, idx=bid>>3; pair = xcd*64 + (idx>>3); qt = idx&7.
// Block = 4 waves; wave owns 16 q rows (q = q0 + lo).
// S^T mfma: lane holds S[q=lo][k = kb*16 + 4*hi + r].
// PV: pa slot j <- st[kc*2+(j>>2)][j&3]  (k_phys = kc*32+(j>>2)*16+4*hi+(j&3));
//     vf slot j <- Vt[dv][same k_phys] via two b64 reads. Slot-aligned
//     contraction makes the shared permutation legal.
// ---------------------------------------------------------------------------
__global__ __launch_bounds__(256,4) void attn_row_mfma(
    const bf16* __restrict__ qkv, bf16* __restrict__ attn,
    const int* __restrict__ sep_ptr)
{
  const int bid = blockIdx.x;
  const int xcd = bid & 7;
  const int idx = bid >> 3;
  const int pair = xcd * 64 + (idx >> 3);
  const int qt = idx & 7;
  const int t = pair >> 2;
  const int h = pair & 3;
  const int sep = *sep_ptr;

  const int tid  = threadIdx.x;
  const int wid  = tid >> 6;
  const int lane = tid & 63;
  const int lo = lane & 15, hi = lane >> 4;

  __shared__ bf16 Ks[2][KBLK][72];
  __shared__ bf16 Vt[2][HDIM][72];

  const int qb = qt * 64;
  const int q0 = qb + wid * 16;

  // Q as B-frag (Q^T): lane holds Q[q0+lo][kc*32 + hi*8 + j]; pre-scaled.
  bf16x8 qf[2];
  {
    const bf16* Qp = qkv + ((size_t)(q0 + lo) * DB + t) * QKV3 + h * HDIM;
    qf[0] = *(const bf16x8*)(Qp + hi * 8);
    qf[1] = *(const bf16x8*)(Qp + 32 + hi * 8);
    #pragma unroll
    for (int kc = 0; kc < 2; ++kc)
      #pragma unroll
      for (int j = 0; j < 8; ++j)
        ((bf16*)&qf[kc])[j] = f2bf(bf2f(((const bf16*)&qf[kc])[j]) * 0.125f);
  }

  const int kr  = tid >> 2;
  const int kc4 = (tid & 3) * 16;
  const int vr  = tid & 63;
  const int vc  = (tid >> 6) * 16;
  const bf16* Kbase = qkv + ((size_t)kr * DB + t) * QKV3 + EE + h * HDIM + kc4;
  const bf16* Vbase = qkv + ((size_t)vr * DB + t) * QKV3 + 2*EE + h * HDIM + vc;
  const size_t kstep = (size_t)KBLK * DB * QKV3;

  f32x4 Oa[4] = {};
  float m_run = -1e30f, l_run = 0.f;

  const int nkt = (qb >= sep) ? ((sep + KBLK - 1) >> 6) : (NN >> 6);
  const bool need_mask = (qb + 64 > sep) && (nkt * KBLK > sep);

  bf16x8 kg0 = *(const bf16x8*)(Kbase);
  bf16x8 kg1 = *(const bf16x8*)(Kbase + 8);
  bf16x8 vg0 = *(const bf16x8*)(Vbase);
  bf16x8 vg1 = *(const bf16x8*)(Vbase + 8);

  for (int kt = 0; kt < nkt; ++kt) {
    const int k0 = kt * KBLK;
    const int p = kt & 1;

    *(bf16x8*)&Ks[p][kr][kc4]     = kg0;
    *(bf16x8*)&Ks[p][kr][kc4 + 8] = kg1;
    #pragma unroll
    for (int j = 0; j < 8; ++j) {
      Vt[p][vc + j][vr]     = ((const bf16*)&vg0)[j];
      Vt[p][vc + 8 + j][vr] = ((const bf16*)&vg1)[j];
    }
    __syncthreads();

    if (kt + 1 < nkt) {
      const size_t off = (size_t)(kt + 1) * kstep;
      kg0 = *(const bf16x8*)(Kbase + off);
      kg1 = *(const bf16x8*)(Kbase + off + 8);
      vg0 = *(const bf16x8*)(Vbase + off);
      vg1 = *(const bf16x8*)(Vbase + off + 8);
    }

    // ---- S^T = K x Q^T : st[kb][r] = S[q=lo][k0 + kb*16 + 4*hi + r] ----
    f32x4 st[4];
    {
      bf16x8 kf[4][2];
      #pragma unroll
      for (int kb = 0; kb < 4; ++kb)
        #pragma unroll
        for (int kc = 0; kc < 2; ++kc)
          kf[kb][kc] = *(const bf16x8*)&Ks[p][kb*16 + lo][kc*32 + hi*8];
      __builtin_amdgcn_s_setprio(1);
      #pragma unroll
      for (int kb = 0; kb < 4; ++kb) {
        st[kb] = (f32x4){0,0,0,0};
        #pragma unroll
        for (int kc = 0; kc < 2; ++kc)
          st[kb] = __builtin_amdgcn_mfma_f32_16x16x32_bf16(
              kf[kb][kc], qf[kc], st[kb], 0, 0, 0);
      }
      __builtin_amdgcn_s_setprio(0);
    }

    // ---- mask (cold path) ----
    if (need_mask && k0 + KBLK > sep) {
      const int qq = q0 + lo;
      #pragma unroll
      for (int kb = 0; kb < 4; ++kb) {
        #pragma unroll
        for (int r = 0; r < 4; ++r) {
          const int kk = k0 + kb*16 + 4*hi + r;
          if (qq >= sep && kk >= sep) st[kb][r] = -1e30f;
        }
      }
    }

    // ---- online softmax (fully in-register; q = lo per lane) ----
    float mx = -1e30f;
    #pragma unroll
    for (int kb = 0; kb < 4; ++kb)
      #pragma unroll
      for (int r = 0; r < 4; ++r) mx = fmaxf(mx, st[kb][r]);
    mx = fmaxf(mx, __shfl_xor(mx, 16));
    mx = fmaxf(mx, __shfl_xor(mx, 32));

    if (__any(mx - m_run > 5.f)) {
      const float mn = fmaxf(m_run, mx);
      const float corr = __expf(m_run - mn);
      m_run = mn;
      l_run *= corr;
      float c4[4];
      #pragma unroll
      for (int r = 0; r < 4; ++r) c4[r] = __shfl(corr, hi*4 + r);
      #pragma unroll
      for (int n = 0; n < 4; ++n)
        #pragma unroll
        for (int r = 0; r < 4; ++r) Oa[n][r] *= c4[r];
    }

    float s0 = 0.f;
    #pragma unroll
    for (int kb = 0; kb < 4; ++kb)
      #pragma unroll
      for (int r = 0; r < 4; ++r) {
        const float pv = __expf(st[kb][r] - m_run);
        st[kb][r] = pv;
        s0 += pv;
      }
    s0 += __shfl_xor(s0, 16);
    s0 += __shfl_xor(s0, 32);
    l_run += s0;

    // ---- pa: in-lane repack (no LDS) ----
    bf16x8 pa[2];
    #pragma unroll
    for (int kc = 0; kc < 2; ++kc)
      #pragma unroll
      for (int j = 0; j < 8; ++j)
        ((bf16*)&pa[kc])[j] = f2bf(st[kc*2 + (j>>2)][j&3]);

    // ---- PV with matching permuted-k V fragments ----
    __builtin_amdgcn_s_setprio(1);
    #pragma unroll
    for (int n = 0; n < 4; ++n) {
      #pragma unroll
      for (int kc = 0; kc < 2; ++kc) {
        const bf16* vrow = &Vt[p][n*16 + lo][0];
        bf16x4 v0 = *(const bf16x4*)(vrow + kc*32 + 4*hi);
        bf16x4 v1 = *(const bf16x4*)(vrow + kc*32 + 16 + 4*hi);
        bf16x8 vf = __builtin_shufflevector(v0, v1, 0,1,2,3,4,5,6,7);
        Oa[n] = __builtin_amdgcn_mfma_f32_16x16x32_bf16(pa[kc], vf, Oa[n], 0, 0, 0);
      }
    }
    __builtin_amdgcn_s_setprio(0);
  }

  // ---- epilogue: lane holds O[q = q0+4*hi+r][dv = n*16+lo] ----
  float linv[4];
  #pragma unroll
  for (int r = 0; r < 4; ++r) linv[r] = 1.f / __shfl(l_run, hi*4 + r);
  #pragma unroll
  for (int r = 0; r < 4; ++r) {
    const int qq = q0 + hi*4 + r;
    bf16* Op = attn + ((size_t)qq * DB + t) * EE + h * HDIM;
    #pragma unroll
    for (int n = 0; n < 4; ++n)
      Op[n*16 + lo] = f2bf(Oa[n][r] * linv[r]);
  }
}

// ---------------------------------------------------------------------------
// Col attention (unchanged): block per (n,b,h); S=32, no mask. Row-token qkv.
// ---------------------------------------------------------------------------
__global__ __launch_bounds__(256) void attn_col_kernel(
    const bf16* __restrict__ qkv, bf16* __restrict__ attn)
{
  const int bid = blockIdx.x;
  const int n = bid >> 4;
  const int b = (bid >> 2) & 3;
  const int h = bid & 3;
  const int tid = threadIdx.x;

  __shared__ float Qs[DD*65], Kx[DD*65], Vs[DD*65];
  __shared__ float P[DD*33];

  {
    const int d = tid >> 3, c = (tid & 7) * 8;
    const size_t base = ((size_t)(n*DB + d*BB + b)) * QKV3 + h*HDIM + c;
    bf16x8 qv = *(const bf16x8*)(qkv + base);
    bf16x8 kv = *(const bf16x8*)(qkv + base + EE);
    bf16x8 vv = *(const bf16x8*)(qkv + base + 2*EE);
    #pragma unroll
    for (int j = 0; j < 8; ++j) {
      Qs[d*65 + c + j] = bf2f(((const bf16*)&qv)[j]);
      Kx[d*65 + c + j] = bf2f(((const bf16*)&kv)[j]);
      Vs[d*65 + c + j] = bf2f(((const bf16*)&vv)[j]);
    }
  }
  __syncthreads();

  const int qi = tid >> 3, kg = tid & 7;
  {
    float s[4] = {0.f, 0.f, 0.f, 0.f};
    for (int e = 0; e < HDIM; ++e) {
      const float qv = Qs[qi*65 + e];
      #pragma unroll
      for (int j = 0; j < 4; ++j)
        s[j] += qv * Kx[(kg*4 + j)*65 + e];
    }
    float mx = -1e30f;
    #pragma unroll
    for (int j = 0; j < 4; ++j) { s[j] *= 0.125f; mx = fmaxf(mx, s[j]); }
    #pragma unroll
    for (int off = 1; off < 8; off <<= 1)
      mx = fmaxf(mx, __shfl_xor(mx, off));
    float sum = 0.f;
    #pragma unroll
    for (int j = 0; j < 4; ++j) { s[j] = __expf(s[j] - mx); sum += s[j]; }
    #pragma unroll
    for (int off = 1; off < 8; off <<= 1)
      sum += __shfl_xor(sum, off);
    const float inv = 1.f / sum;
    #pragma unroll
    for (int j = 0; j < 4; ++j)
      P[qi*33 + kg*4 + j] = s[j] * inv;
  }
  __syncthreads();

  {
    const int eb = (tid & 7) * 8;
    float acc[8] = {};
    for (int ki = 0; ki < DD; ++ki) {
      const float pv = P[qi*33 + ki];
      #pragma unroll
      for (int j = 0; j < 8; ++j)
        acc[j] += pv * Vs[ki*65 + eb + j];
    }
    bf16x8 o;
    #pragma unroll
    for (int j = 0; j < 8; ++j)
      ((bf16*)&o)[j] = f2bf(acc[j]);
    *(bf16x8*)(attn + ((size_t)(n*DB + qi*BB + b)) * EE + h*HDIM + eb) = o;
  }
}

// ---------------------------------------------------------------------------
// Final: out = LayerNorm(src_bf + r + c).  4 tokens/block, shuffle reduce.
// ---------------------------------------------------------------------------
__global__ __launch_bounds__(256) void ln_kernel(
    const bf16* __restrict__ srcb, const bf16* __restrict__ rp,
    const bf16* __restrict__ cp, const float* __restrict__ g,
    const float* __restrict__ b, float* __restrict__ out)
{
  const int m = blockIdx.x * 4 + (threadIdx.x >> 6);
  const int lane = threadIdx.x & 63;
  const bf16x4 s4 = ((const bf16x4*)srcb)[(size_t)m*64 + lane];
  const bf16x4 r4 = ((const bf16x4*)rp)[(size_t)m*64 + lane];
  const bf16x4 c4 = ((const bf16x4*)cp)[(size_t)m*64 + lane];
  float x[4];
  #pragma unroll
  for (int j = 0; j < 4; ++j)
    x[j] = bf2f(((const bf16*)&s4)[j]) + bf2f(((const bf16*)&r4)[j])
         + bf2f(((const bf16*)&c4)[j]);
  float sum = x[0] + x[1] + x[2] + x[3];
  #pragma unroll
  for (int off = 1; off < 64; off <<= 1) sum += __shfl_xor(sum, off);
  const float mu = sum * (1.f/EE);
  float d[4];
  #pragma unroll
  for (int j = 0; j < 4; ++j) d[j] = x[j] - mu;
  float ss = d[0]*d[0] + d[1]*d[1] + d[2]*d[2] + d[3]*d[3];
  #pragma unroll
  for (int off = 1; off < 64; off <<= 1) ss += __shfl_xor(ss, off);
  const float rstd = rsqrtf(ss * (1.f/EE) + 1e-5f);
  const float4 g4 = ((const float4*)g)[lane];
  const float4 b4 = ((const float4*)b)[lane];
  float4 o;
  o.x = d[0] * rstd * g4.x + b4.x;
  o.y = d[1] * rstd * g4.y + b4.y;
  o.z = d[2] * rstd * g4.z + b4.z;
  o.w = d[3] * rstd * g4.w + b4.w;
  ((float4*)out)[(size_t)m*64 + lane] = o;
}

// ---------------------------------------------------------------------------
extern "C" void kernel_launch(void* const* d_in, const int* in_sizes, int n_in,
                              void* d_out, int out_size, void* d_ws, size_t ws_size,
                              hipStream_t stream)
{
  const float* src      = (const float*)d_in[0];
  const float* w_in_row = (const float*)d_in[1];
  const float* b_in_row = (const float*)d_in[2];
  const float* w_out_row= (const float*)d_in[3];
  const float* b_out_row= (const float*)d_in[4];
  const float* w_in_col = (const float*)d_in[5];
  const float* b_in_col = (const float*)d_in[6];
  const float* w_out_col= (const float*)d_in[7];
  const float* b_out_col= (const float*)d_in[8];
  const float* ln_g     = (const float*)d_in[9];
  const float* ln_b     = (const float*)d_in[10];
  const int*   sep_ptr  = (const int*)d_in[12];
  float* out = (float*)d_out;

  char* ws = (char*)d_ws;
  bf16*  qkv    = (bf16*)(ws);                       // 100663296
  bf16*  attnX  = (bf16*)(ws + 100663296);           //  33554432
  bf16*  r_out  = (bf16*)(ws + 134217728);           //  33554432
  bf16*  c_out  = (bf16*)(ws + 167772160);           //  33554432
  bf16*  src_bf = (bf16*)(ws + 201326592);           //  33554432
  bf16*  wbf_ir = (bf16*)(ws + 234881024);
  bf16*  wbf_or = (bf16*)(ws + 235274240);
  bf16*  wbf_ic = (bf16*)(ws + 235405312);
  bf16*  wbf_oc = (bf16*)(ws + 235798528);

  dim3 blk(256);

  // converts
  cvt_kernel<<<dim3(MTOK*EE/8/256), blk, 0, stream>>>(src, src_bf, MTOK*EE);
  cvt_w_kernel<<<dim3(256), blk, 0, stream>>>(
      w_in_row, w_out_row, w_in_col, w_out_col, wbf_ir, wbf_or, wbf_ic, wbf_oc);

  // row path
  gemm_mfma<6,QKV3><<<dim3(512*6), blk, 0, stream>>>(src_bf, wbf_ir, b_in_row, qkv);
  attn_row_mfma<<<dim3(4096), blk, 0, stream>>>(qkv, attnX, sep_ptr);
  gemm_mfma<2,EE><<<dim3(512*2), blk, 0, stream>>>(attnX, wbf_or, b_out_row, r_out);

  // col path (qkv + attnX reused, stream-ordered)
  gemm_mfma<6,QKV3><<<dim3(512*6), blk, 0, stream>>>(src_bf, wbf_ic, b_in_col, qkv);
  attn_col_kernel<<<dim3(NN*BB*HH), blk, 0, stream>>>(qkv, attnX);
  gemm_mfma<2,EE><<<dim3(512*2), blk, 0, stream>>>(attnX, wbf_oc, b_out_col, c_out);

  // residual + LayerNorm
  ln_kernel<<<dim3(MTOK/4), blk, 0, stream>>>(src_bf, r_out, c_out, ln_g, ln_b, out);
}

// Round 7
// 264.073 us; speedup vs baseline: 1.5220x; 1.2907x over previous
//
#include <hip/hip_runtime.h>
#include <hip/hip_bf16.h>
#include <cstdint>
#include <cstddef>

// AxialAttentionModule round 7:
//  - attn_col rewritten as MFMA kernel: block per (n,b), 4 waves = 4 heads,
//    swapped S^T = mfma(K,Q) with Q/K frags direct from global, single-pass
//    in-register softmax, V^T staged in LDS, permuted-k PV (row-kernel trick).
//  - everything else unchanged from round 6.
// Fixed shapes: N=512 D=32 B=4 E=256 H=4 HD=64.

typedef __hip_bfloat16 bf16;
typedef __attribute__((ext_vector_type(8))) short bf16x8;
typedef __attribute__((ext_vector_type(8))) short short8;
typedef __attribute__((ext_vector_type(4))) short bf16x4;
typedef __attribute__((ext_vector_type(4))) float f32x4;

#define NN 512
#define DD 32
#define BB 4
#define EE 256
#define HH 4
#define HDIM 64
#define DB (DD*BB)        // 128
#define MTOK (NN*DD*BB)   // 65536
#define QKV3 (3*EE)       // 768
#define KBLK 64

__device__ __forceinline__ float bf2f(bf16 x){ return __bfloat162float(x); }
__device__ __forceinline__ bf16 f2bf(float x){ return __float2bfloat16(x); }

#define AS1C(p) ((const __attribute__((address_space(1))) void*)(p))
#define AS3(p)  ((__attribute__((address_space(3))) void*)(p))

// ---------------------------------------------------------------------------
// fp32 -> bf16 bulk convert (src)
// ---------------------------------------------------------------------------
__global__ __launch_bounds__(256) void cvt_kernel(
    const float* __restrict__ in, bf16* __restrict__ out, int n)
{
  int i = (blockIdx.x * 256 + threadIdx.x) * 8;
  if (i >= n) return;
  const float* p = in + i;
  short8 o;
  #pragma unroll
  for (int j = 0; j < 8; ++j)
    ((bf16*)&o)[j] = f2bf(p[j]);
  *(short8*)(out + i) = o;
}

// ---------------------------------------------------------------------------
// all 4 weight converts in one launch
// ---------------------------------------------------------------------------
__global__ __launch_bounds__(256) void cvt_w_kernel(
    const float* __restrict__ ir, const float* __restrict__ orr,
    const float* __restrict__ ic, const float* __restrict__ oc,
    bf16* __restrict__ d_ir, bf16* __restrict__ d_or,
    bf16* __restrict__ d_ic, bf16* __restrict__ d_oc)
{
  const int b = blockIdx.x;
  const float* src; bf16* dst; int off;
  if (b < 96)       { src = ir;  dst = d_ir; off = b; }
  else if (b < 128) { src = orr; dst = d_or; off = b - 96; }
  else if (b < 224) { src = ic;  dst = d_ic; off = b - 128; }
  else              { src = oc;  dst = d_oc; off = b - 224; }
  const int i = (off * 256 + threadIdx.x) * 8;
  const float* p = src + i;
  short8 o;
  #pragma unroll
  for (int j = 0; j < 8; ++j)
    ((bf16*)&o)[j] = f2bf(p[j]);
  *(short8*)(dst + i) = o;
}

// ---------------------------------------------------------------------------
// MFMA GEMM (unchanged): C[M, NOUT] = A[M,256] @ W[NOUT,256]^T + bias.
// ---------------------------------------------------------------------------
template<int NT, int NOUT>
__global__ __launch_bounds__(256,2) void gemm_mfma(
    const bf16* __restrict__ A, const bf16* __restrict__ W,
    const float* __restrict__ bias, bf16* __restrict__ C)
{
  __shared__ bf16 As[128][64];
  __shared__ bf16 Bs[128][64];
  const int bid = blockIdx.x;
  const int xcd = bid & 7;
  const int i0  = bid >> 3;
  const int bm  = xcd * 64 + i0 / NT;
  const int bn  = i0 % NT;

  const int tid  = threadIdx.x;
  const int wid  = tid >> 6;
  const int lane = tid & 63;
  const int lo = lane & 15, hi = lane >> 4;
  const int wr = wid >> 1, wc = wid & 1;

  const int srow = lane >> 3;
  const int slin = (lane & 7) << 4;
  const int ssrc = slin ^ (srow << 4);

  f32x4 acc[4][4] = {};

  for (int k0 = 0; k0 < 256; k0 += 64) {
    __syncthreads();
    #pragma unroll
    for (int i = 0; i < 4; ++i) {
      const int r = wid * 32 + i * 8 + srow;
      const int m = bm * 128 + r;
      const char* gpA = (const char*)(A + (size_t)m * EE + k0) + ssrc;
      __builtin_amdgcn_global_load_lds(AS1C(gpA), AS3(&As[wid*32 + i*8][0]), 16, 0, 0);
      const int wn = bn * 128 + r;
      const char* gpB = (const char*)(W + (size_t)wn * EE + k0) + ssrc;
      __builtin_amdgcn_global_load_lds(AS1C(gpB), AS3(&Bs[wid*32 + i*8][0]), 16, 0, 0);
    }
    __syncthreads();

    #pragma unroll
    for (int kc = 0; kc < 2; ++kc) {
      const int cc = kc * 64 + hi * 16;
      bf16x8 af[4], bfr[4];
      #pragma unroll
      for (int i = 0; i < 4; ++i) {
        const int ra = wr * 64 + i * 16 + lo;
        af[i]  = *(const bf16x8*)((const char*)&As[ra][0] + (cc ^ ((ra & 7) << 4)));
        const int rb = wc * 64 + i * 16 + lo;
        bfr[i] = *(const bf16x8*)((const char*)&Bs[rb][0] + (cc ^ ((rb & 7) << 4)));
      }
      __builtin_amdgcn_s_setprio(1);
      #pragma unroll
      for (int mi = 0; mi < 4; ++mi)
        #pragma unroll
        for (int ni = 0; ni < 4; ++ni)
          acc[mi][ni] = __builtin_amdgcn_mfma_f32_16x16x32_bf16(
              af[mi], bfr[ni], acc[mi][ni], 0, 0, 0);
      __builtin_amdgcn_s_setprio(0);
    }
  }

  float bv[4];
  #pragma unroll
  for (int ni = 0; ni < 4; ++ni)
    bv[ni] = bias[bn * 128 + wc * 64 + ni * 16 + lo];

  #pragma unroll
  for (int mi = 0; mi < 4; ++mi) {
    #pragma unroll
    for (int r = 0; r < 4; ++r) {
      const int m = bm * 128 + wr * 64 + mi * 16 + hi * 4 + r;
      #pragma unroll
      for (int ni = 0; ni < 4; ++ni) {
        const int col = bn * 128 + wc * 64 + ni * 16 + lo;
        C[(size_t)m * NOUT + col] = f2bf(acc[mi][ni][r] + bv[ni]);
      }
    }
  }
}

// ---------------------------------------------------------------------------
// Row attention v3 (unchanged from round 6): swapped QK^T, in-register
// softmax, permuted-k PV.
// ---------------------------------------------------------------------------
__global__ __launch_bounds__(256,4) void attn_row_mfma(
    const bf16* __restrict__ qkv, bf16* __restrict__ attn,
    const int* __restrict__ sep_ptr)
{
  const int bid = blockIdx.x;
  const int xcd = bid & 7;
  const int idx = bid >> 3;
  const int pair = xcd * 64 + (idx >> 3);
  const int qt = idx & 7;
  const int t = pair >> 2;
  const int h = pair & 3;
  const int sep = *sep_ptr;

  const int tid  = threadIdx.x;
  const int wid  = tid >> 6;
  const int lane = tid & 63;
  const int lo = lane & 15, hi = lane >> 4;

  __shared__ bf16 Ks[2][KBLK][72];
  __shared__ bf16 Vt[2][HDIM][72];

  const int qb = qt * 64;
  const int q0 = qb + wid * 16;

  bf16x8 qf[2];
  {
    const bf16* Qp = qkv + ((size_t)(q0 + lo) * DB + t) * QKV3 + h * HDIM;
    qf[0] = *(const bf16x8*)(Qp + hi * 8);
    qf[1] = *(const bf16x8*)(Qp + 32 + hi * 8);
    #pragma unroll
    for (int kc = 0; kc < 2; ++kc)
      #pragma unroll
      for (int j = 0; j < 8; ++j)
        ((bf16*)&qf[kc])[j] = f2bf(bf2f(((const bf16*)&qf[kc])[j]) * 0.125f);
  }

  const int kr  = tid >> 2;
  const int kc4 = (tid & 3) * 16;
  const int vr  = tid & 63;
  const int vc  = (tid >> 6) * 16;
  const bf16* Kbase = qkv + ((size_t)kr * DB + t) * QKV3 + EE + h * HDIM + kc4;
  const bf16* Vbase = qkv + ((size_t)vr * DB + t) * QKV3 + 2*EE + h * HDIM + vc;
  const size_t kstep = (size_t)KBLK * DB * QKV3;

  f32x4 Oa[4] = {};
  float m_run = -1e30f, l_run = 0.f;

  const int nkt = (qb >= sep) ? ((sep + KBLK - 1) >> 6) : (NN >> 6);
  const bool need_mask = (qb + 64 > sep) && (nkt * KBLK > sep);

  bf16x8 kg0 = *(const bf16x8*)(Kbase);
  bf16x8 kg1 = *(const bf16x8*)(Kbase + 8);
  bf16x8 vg0 = *(const bf16x8*)(Vbase);
  bf16x8 vg1 = *(const bf16x8*)(Vbase + 8);

  for (int kt = 0; kt < nkt; ++kt) {
    const int k0 = kt * KBLK;
    const int p = kt & 1;

    *(bf16x8*)&Ks[p][kr][kc4]     = kg0;
    *(bf16x8*)&Ks[p][kr][kc4 + 8] = kg1;
    #pragma unroll
    for (int j = 0; j < 8; ++j) {
      Vt[p][vc + j][vr]     = ((const bf16*)&vg0)[j];
      Vt[p][vc + 8 + j][vr] = ((const bf16*)&vg1)[j];
    }
    __syncthreads();

    if (kt + 1 < nkt) {
      const size_t off = (size_t)(kt + 1) * kstep;
      kg0 = *(const bf16x8*)(Kbase + off);
      kg1 = *(const bf16x8*)(Kbase + off + 8);
      vg0 = *(const bf16x8*)(Vbase + off);
      vg1 = *(const bf16x8*)(Vbase + off + 8);
    }

    f32x4 st[4];
    {
      bf16x8 kf[4][2];
      #pragma unroll
      for (int kb = 0; kb < 4; ++kb)
        #pragma unroll
        for (int kc = 0; kc < 2; ++kc)
          kf[kb][kc] = *(const bf16x8*)&Ks[p][kb*16 + lo][kc*32 + hi*8];
      __builtin_amdgcn_s_setprio(1);
      #pragma unroll
      for (int kb = 0; kb < 4; ++kb) {
        st[kb] = (f32x4){0,0,0,0};
        #pragma unroll
        for (int kc = 0; kc < 2; ++kc)
          st[kb] = __builtin_amdgcn_mfma_f32_16x16x32_bf16(
              kf[kb][kc], qf[kc], st[kb], 0, 0, 0);
      }
      __builtin_amdgcn_s_setprio(0);
    }

    if (need_mask && k0 + KBLK > sep) {
      const int qq = q0 + lo;
      #pragma unroll
      for (int kb = 0; kb < 4; ++kb) {
        #pragma unroll
        for (int r = 0; r < 4; ++r) {
          const int kk = k0 + kb*16 + 4*hi + r;
          if (qq >= sep && kk >= sep) st[kb][r] = -1e30f;
        }
      }
    }

    float mx = -1e30f;
    #pragma unroll
    for (int kb = 0; kb < 4; ++kb)
      #pragma unroll
      for (int r = 0; r < 4; ++r) mx = fmaxf(mx, st[kb][r]);
    mx = fmaxf(mx, __shfl_xor(mx, 16));
    mx = fmaxf(mx, __shfl_xor(mx, 32));

    if (__any(mx - m_run > 5.f)) {
      const float mn = fmaxf(m_run, mx);
      const float corr = __expf(m_run - mn);
      m_run = mn;
      l_run *= corr;
      float c4[4];
      #pragma unroll
      for (int r = 0; r < 4; ++r) c4[r] = __shfl(corr, hi*4 + r);
      #pragma unroll
      for (int n = 0; n < 4; ++n)
        #pragma unroll
        for (int r = 0; r < 4; ++r) Oa[n][r] *= c4[r];
    }

    float s0 = 0.f;
    #pragma unroll
    for (int kb = 0; kb < 4; ++kb)
      #pragma unroll
      for (int r = 0; r < 4; ++r) {
        const float pv = __expf(st[kb][r] - m_run);
        st[kb][r] = pv;
        s0 += pv;
      }
    s0 += __shfl_xor(s0, 16);
    s0 += __shfl_xor(s0, 32);
    l_run += s0;

    bf16x8 pa[2];
    #pragma unroll
    for (int kc = 0; kc < 2; ++kc)
      #pragma unroll
      for (int j = 0; j < 8; ++j)
        ((bf16*)&pa[kc])[j] = f2bf(st[kc*2 + (j>>2)][j&3]);

    __builtin_amdgcn_s_setprio(1);
    #pragma unroll
    for (int n = 0; n < 4; ++n) {
      #pragma unroll
      for (int kc = 0; kc < 2; ++kc) {
        const bf16* vrow = &Vt[p][n*16 + lo][0];
        bf16x4 v0 = *(const bf16x4*)(vrow + kc*32 + 4*hi);
        bf16x4 v1 = *(const bf16x4*)(vrow + kc*32 + 16 + 4*hi);
        bf16x8 vf = __builtin_shufflevector(v0, v1, 0,1,2,3,4,5,6,7);
        Oa[n] = __builtin_amdgcn_mfma_f32_16x16x32_bf16(pa[kc], vf, Oa[n], 0, 0, 0);
      }
    }
    __builtin_amdgcn_s_setprio(0);
  }

  float linv[4];
  #pragma unroll
  for (int r = 0; r < 4; ++r) linv[r] = 1.f / __shfl(l_run, hi*4 + r);
  #pragma unroll
  for (int r = 0; r < 4; ++r) {
    const int qq = q0 + hi*4 + r;
    bf16* Op = attn + ((size_t)qq * DB + t) * EE + h * HDIM;
    #pragma unroll
    for (int n = 0; n < 4; ++n)
      Op[n*16 + lo] = f2bf(Oa[n][r] * linv[r]);
  }
}

// ---------------------------------------------------------------------------
// Col attention v2: MFMA. Block per (n,b) [grid 2048], wave = head.
// S=32 over D axis, no mask, single-pass softmax.
// Swapped S^T: st[kt][mt] = mfma(K-frag, Q-frag); lane holds
//   S[q = mt*16+lo][k = kt*16 + 4*hi + r].
// Q/K frags loaded directly from global (row n*DB + row*4 + b).
// V^T staged in LDS (Vt[h][d=64][k=32], stride 40); PV uses the permuted-k
// bf16x4-pair trick (same as row kernel, single kc since K=32).
// ---------------------------------------------------------------------------
__global__ __launch_bounds__(256) void attn_col_mfma(
    const bf16* __restrict__ qkv, bf16* __restrict__ attn)
{
  const int bid = blockIdx.x;          // n*4 + b
  const int n = bid >> 2;
  const int b = bid & 3;
  const int tid = threadIdx.x;
  const int h = tid >> 6;              // wave = head
  const int lane = tid & 63;
  const int lo = lane & 15, hi = lane >> 4;

  __shared__ bf16 Vt[4][64][40];

  // ---- stage V^T: thread (k = tid&31, hh = (tid>>6), dh = (tid>>5)&1) ----
  {
    const int k  = tid & 31;
    const int hh = tid >> 6;
    const int dh = ((tid >> 5) & 1) * 32;
    const bf16* Vp = qkv + ((size_t)(n*DB + k*4 + b)) * QKV3 + 2*EE + hh*64 + dh;
    #pragma unroll
    for (int c = 0; c < 4; ++c) {
      bf16x8 vv = *(const bf16x8*)(Vp + c*8);
      #pragma unroll
      for (int j = 0; j < 8; ++j)
        Vt[hh][dh + c*8 + j][k] = ((const bf16*)&vv)[j];
    }
  }

  // ---- Q (pre-scaled) and K fragments, direct from global ----
  bf16x8 qf[2][2], kf[2][2];
  #pragma unroll
  for (int mt = 0; mt < 2; ++mt) {
    const bf16* Qp = qkv + ((size_t)(n*DB + (mt*16 + lo)*4 + b)) * QKV3 + h*64;
    #pragma unroll
    for (int kc = 0; kc < 2; ++kc) {
      bf16x8 v = *(const bf16x8*)(Qp + kc*32 + hi*8);
      #pragma unroll
      for (int j = 0; j < 8; ++j)
        ((bf16*)&v)[j] = f2bf(bf2f(((const bf16*)&v)[j]) * 0.125f);
      qf[mt][kc] = v;
    }
    const bf16* Kp = Qp + EE;
    kf[mt][0] = *(const bf16x8*)(Kp + hi*8);
    kf[mt][1] = *(const bf16x8*)(Kp + 32 + hi*8);
  }
  __syncthreads();

  // ---- S^T tiles ----
  f32x4 st[2][2];   // [kt][mt]
  #pragma unroll
  for (int kt = 0; kt < 2; ++kt)
    #pragma unroll
    for (int mt = 0; mt < 2; ++mt) {
      f32x4 a = {0,0,0,0};
      a = __builtin_amdgcn_mfma_f32_16x16x32_bf16(kf[kt][0], qf[mt][0], a, 0, 0, 0);
      a = __builtin_amdgcn_mfma_f32_16x16x32_bf16(kf[kt][1], qf[mt][1], a, 0, 0, 0);
      st[kt][mt] = a;
    }

  // ---- single-pass softmax per mt (k fully resident) ----
  float l[2];
  #pragma unroll
  for (int mt = 0; mt < 2; ++mt) {
    float mx = -1e30f;
    #pragma unroll
    for (int kt = 0; kt < 2; ++kt)
      #pragma unroll
      for (int r = 0; r < 4; ++r) mx = fmaxf(mx, st[kt][mt][r]);
    mx = fmaxf(mx, __shfl_xor(mx, 16));
    mx = fmaxf(mx, __shfl_xor(mx, 32));
    float s0 = 0.f;
    #pragma unroll
    for (int kt = 0; kt < 2; ++kt)
      #pragma unroll
      for (int r = 0; r < 4; ++r) {
        const float pv = __expf(st[kt][mt][r] - mx);
        st[kt][mt][r] = pv;
        s0 += pv;
      }
    s0 += __shfl_xor(s0, 16);
    s0 += __shfl_xor(s0, 32);
    l[mt] = s0;
  }

  // ---- P repack (in-lane): pa[mt] slot j <- st[j>>2][mt][j&3] ----
  bf16x8 pa[2];
  #pragma unroll
  for (int mt = 0; mt < 2; ++mt)
    #pragma unroll
    for (int j = 0; j < 8; ++j)
      ((bf16*)&pa[mt])[j] = f2bf(st[j>>2][mt][j&3]);

  // ---- PV with permuted-k V frags ----
  f32x4 Oa[2][4] = {};
  #pragma unroll
  for (int nn = 0; nn < 4; ++nn) {
    const bf16* vrow = &Vt[h][nn*16 + lo][0];
    bf16x4 v0 = *(const bf16x4*)(vrow + 4*hi);
    bf16x4 v1 = *(const bf16x4*)(vrow + 16 + 4*hi);
    bf16x8 vf = __builtin_shufflevector(v0, v1, 0,1,2,3,4,5,6,7);
    Oa[0][nn] = __builtin_amdgcn_mfma_f32_16x16x32_bf16(pa[0], vf, Oa[0][nn], 0, 0, 0);
    Oa[1][nn] = __builtin_amdgcn_mfma_f32_16x16x32_bf16(pa[1], vf, Oa[1][nn], 0, 0, 0);
  }

  // ---- epilogue: lane holds O[q = mt*16 + 4*hi + r][dv = nn*16 + lo] ----
  float linv[2][4];
  #pragma unroll
  for (int mt = 0; mt < 2; ++mt)
    #pragma unroll
    for (int r = 0; r < 4; ++r)
      linv[mt][r] = 1.f / __shfl(l[mt], hi*4 + r);
  #pragma unroll
  for (int mt = 0; mt < 2; ++mt) {
    #pragma unroll
    for (int r = 0; r < 4; ++r) {
      const int q = mt*16 + hi*4 + r;
      bf16* Op = attn + ((size_t)(n*DB + q*4 + b)) * EE + h*64;
      #pragma unroll
      for (int nn = 0; nn < 4; ++nn)
        Op[nn*16 + lo] = f2bf(Oa[mt][nn][r] * linv[mt][r]);
    }
  }
}

// ---------------------------------------------------------------------------
// Final: out = LayerNorm(src_bf + r + c).  4 tokens/block, shuffle reduce.
// ---------------------------------------------------------------------------
__global__ __launch_bounds__(256) void ln_kernel(
    const bf16* __restrict__ srcb, const bf16* __restrict__ rp,
    const bf16* __restrict__ cp, const float* __restrict__ g,
    const float* __restrict__ b, float* __restrict__ out)
{
  const int m = blockIdx.x * 4 + (threadIdx.x >> 6);
  const int lane = threadIdx.x & 63;
  const bf16x4 s4 = ((const bf16x4*)srcb)[(size_t)m*64 + lane];
  const bf16x4 r4 = ((const bf16x4*)rp)[(size_t)m*64 + lane];
  const bf16x4 c4 = ((const bf16x4*)cp)[(size_t)m*64 + lane];
  float x[4];
  #pragma unroll
  for (int j = 0; j < 4; ++j)
    x[j] = bf2f(((const bf16*)&s4)[j]) + bf2f(((const bf16*)&r4)[j])
         + bf2f(((const bf16*)&c4)[j]);
  float sum = x[0] + x[1] + x[2] + x[3];
  #pragma unroll
  for (int off = 1; off < 64; off <<= 1) sum += __shfl_xor(sum, off);
  const float mu = sum * (1.f/EE);
  float d[4];
  #pragma unroll
  for (int j = 0; j < 4; ++j) d[j] = x[j] - mu;
  float ss = d[0]*d[0] + d[1]*d[1] + d[2]*d[2] + d[3]*d[3];
  #pragma unroll
  for (int off = 1; off < 64; off <<= 1) ss += __shfl_xor(ss, off);
  const float rstd = rsqrtf(ss * (1.f/EE) + 1e-5f);
  const float4 g4 = ((const float4*)g)[lane];
  const float4 b4 = ((const float4*)b)[lane];
  float4 o;
  o.x = d[0] * rstd * g4.x + b4.x;
  o.y = d[1] * rstd * g4.y + b4.y;
  o.z = d[2] * rstd * g4.z + b4.z;
  o.w = d[3] * rstd * g4.w + b4.w;
  ((float4*)out)[(size_t)m*64 + lane] = o;
}

// ---------------------------------------------------------------------------
extern "C" void kernel_launch(void* const* d_in, const int* in_sizes, int n_in,
                              void* d_out, int out_size, void* d_ws, size_t ws_size,
                              hipStream_t stream)
{
  const float* src      = (const float*)d_in[0];
  const float* w_in_row = (const float*)d_in[1];
  const float* b_in_row = (const float*)d_in[2];
  const float* w_out_row= (const float*)d_in[3];
  const float* b_out_row= (const float*)d_in[4];
  const float* w_in_col = (const float*)d_in[5];
  const float* b_in_col = (const float*)d_in[6];
  const float* w_out_col= (const float*)d_in[7];
  const float* b_out_col= (const float*)d_in[8];
  const float* ln_g     = (const float*)d_in[9];
  const float* ln_b     = (const float*)d_in[10];
  const int*   sep_ptr  = (const int*)d_in[12];
  float* out = (float*)d_out;

  char* ws = (char*)d_ws;
  bf16*  qkv    = (bf16*)(ws);                       // 100663296
  bf16*  attnX  = (bf16*)(ws + 100663296);           //  33554432
  bf16*  r_out  = (bf16*)(ws + 134217728);           //  33554432
  bf16*  c_out  = (bf16*)(ws + 167772160);           //  33554432
  bf16*  src_bf = (bf16*)(ws + 201326592);           //  33554432
  bf16*  wbf_ir = (bf16*)(ws + 234881024);
  bf16*  wbf_or = (bf16*)(ws + 235274240);
  bf16*  wbf_ic = (bf16*)(ws + 235405312);
  bf16*  wbf_oc = (bf16*)(ws + 235798528);

  dim3 blk(256);

  // converts
  cvt_kernel<<<dim3(MTOK*EE/8/256), blk, 0, stream>>>(src, src_bf, MTOK*EE);
  cvt_w_kernel<<<dim3(256), blk, 0, stream>>>(
      w_in_row, w_out_row, w_in_col, w_out_col, wbf_ir, wbf_or, wbf_ic, wbf_oc);

  // row path
  gemm_mfma<6,QKV3><<<dim3(512*6), blk, 0, stream>>>(src_bf, wbf_ir, b_in_row, qkv);
  attn_row_mfma<<<dim3(4096), blk, 0, stream>>>(qkv, attnX, sep_ptr);
  gemm_mfma<2,EE><<<dim3(512*2), blk, 0, stream>>>(attnX, wbf_or, b_out_row, r_out);

  // col path (qkv + attnX reused, stream-ordered)
  gemm_mfma<6,QKV3><<<dim3(512*6), blk, 0, stream>>>(src_bf, wbf_ic, b_in_col, qkv);
  attn_col_mfma<<<dim3(NN*BB), blk, 0, stream>>>(qkv, attnX);
  gemm_mfma<2,EE><<<dim3(512*2), blk, 0, stream>>>(attnX, wbf_oc, b_out_col, c_out);

  // residual + LayerNorm
  ln_kernel<<<dim3(MTOK/4), blk, 0, stream>>>(src_bf, r_out, c_out, ln_g, ln_b, out);
}

// Round 8
// 256.961 us; speedup vs baseline: 1.5641x; 1.0277x over previous
//
#include <hip/hip_runtime.h>
#include <hip/hip_bf16.h>
#include <cstdint>
#include <cstddef>

// AxialAttentionModule round 8:
//  - attn: single fused launch (row blocks + col blocks), row body
//    single-buffered LDS (18.4KB -> 8 blocks/CU) with async reg-staging.
//  - fast bf16 pack ((u+0x8000)>>16) everywhere instead of RNE f2bf.
//  - fused QKV GEMM (N=1536, per-bn W select) + fused out-proj GEMM,
//    IF ws_size >= 256MiB (runtime branch); else sequential fallback.
// Fixed shapes: N=512 D=32 B=4 E=256 H=4 HD=64.

typedef __hip_bfloat16 bf16;
typedef __attribute__((ext_vector_type(8))) short bf16x8;
typedef __attribute__((ext_vector_type(8))) short short8;
typedef __attribute__((ext_vector_type(4))) short bf16x4;
typedef __attribute__((ext_vector_type(4))) float f32x4;

#define NN 512
#define DD 32
#define BB 4
#define EE 256
#define HH 4
#define HDIM 64
#define DB (DD*BB)        // 128
#define MTOK (NN*DD*BB)   // 65536
#define KBLK 64

__device__ __forceinline__ float bf2f(bf16 x){ return __bfloat162float(x); }
// fast f32->bf16 (round-half-up): 2 VALU vs ~8 for RNE
__device__ __forceinline__ short pkbf(float x){
  union { float f; uint32_t u; } c; c.f = x;
  return (short)((c.u + 0x8000u) >> 16);
}

#define AS1C(p) ((const __attribute__((address_space(1))) void*)(p))
#define AS3(p)  ((__attribute__((address_space(3))) void*)(p))

// ---------------------------------------------------------------------------
// fp32 -> bf16 bulk convert
// ---------------------------------------------------------------------------
__global__ __launch_bounds__(256) void cvt_kernel(
    const float* __restrict__ in, bf16* __restrict__ out, int n)
{
  int i = (blockIdx.x * 256 + threadIdx.x) * 8;
  if (i >= n) return;
  const float* p = in + i;
  short8 o;
  #pragma unroll
  for (int j = 0; j < 8; ++j) ((short*)&o)[j] = pkbf(p[j]);
  *(short8*)(out + i) = o;
}

// in-proj weights (768x256 each): 96+96 blocks
__global__ __launch_bounds__(256) void cvt_w_kernel(
    const float* __restrict__ ir, const float* __restrict__ ic,
    bf16* __restrict__ d_ir, bf16* __restrict__ d_ic)
{
  const int b = blockIdx.x;
  const float* src = (b < 96) ? ir : ic;
  bf16* dst = (b < 96) ? d_ir : d_ic;
  const int off = (b < 96) ? b : b - 96;
  const int i = (off * 256 + threadIdx.x) * 8;
  const float* p = src + i;
  short8 o;
  #pragma unroll
  for (int j = 0; j < 8; ++j) ((short*)&o)[j] = pkbf(p[j]);
  *(short8*)(dst + i) = o;
}

// out-proj weights (256x256 each): 32+32 blocks
__global__ __launch_bounds__(256) void cvt_w2_kernel(
    const float* __restrict__ orr, const float* __restrict__ oc,
    bf16* __restrict__ d_or, bf16* __restrict__ d_oc)
{
  const int b = blockIdx.x;
  const float* src = (b < 32) ? orr : oc;
  bf16* dst = (b < 32) ? d_or : d_oc;
  const int off = (b < 32) ? b : b - 32;
  const int i = (off * 256 + threadIdx.x) * 8;
  const float* p = src + i;
  short8 o;
  #pragma unroll
  for (int j = 0; j < 8; ++j) ((short*)&o)[j] = pkbf(p[j]);
  *(short8*)(dst + i) = o;
}

// ---------------------------------------------------------------------------
// QKV GEMM: C[M, nout] = A[M,256] @ Wsel^T + bias_sel.  128x128 tile, BK=64.
// bn < nt1 -> (W1,b1) else (W2,b2) with local n index. XOR-swizzled LDS.
// ---------------------------------------------------------------------------
template<int NT>
__global__ __launch_bounds__(256,2) void gemm_qkv(
    const bf16* __restrict__ A, const bf16* __restrict__ W1,
    const bf16* __restrict__ W2, const float* __restrict__ b1,
    const float* __restrict__ b2, bf16* __restrict__ C,
    const int nt1, const int nout)
{
  __shared__ bf16 As[128][64];
  __shared__ bf16 Bs[128][64];
  const int bid = blockIdx.x;
  const int xcd = bid & 7;
  const int i0  = bid >> 3;
  const int bm  = xcd * 64 + i0 / NT;
  const int bn  = i0 % NT;
  const int lbn = (bn < nt1) ? bn : bn - nt1;
  const bf16* W = (bn < nt1) ? W1 : W2;
  const float* bias = (bn < nt1) ? b1 : b2;

  const int tid  = threadIdx.x;
  const int wid  = tid >> 6;
  const int lane = tid & 63;
  const int lo = lane & 15, hi = lane >> 4;
  const int wr = wid >> 1, wc = wid & 1;

  const int srow = lane >> 3;
  const int ssrc = ((lane & 7) << 4) ^ (srow << 4);

  f32x4 acc[4][4] = {};

  for (int k0 = 0; k0 < 256; k0 += 64) {
    __syncthreads();
    #pragma unroll
    for (int i = 0; i < 4; ++i) {
      const int r = wid * 32 + i * 8 + srow;
      const int m = bm * 128 + r;
      const char* gpA = (const char*)(A + (size_t)m * EE + k0) + ssrc;
      __builtin_amdgcn_global_load_lds(AS1C(gpA), AS3(&As[wid*32 + i*8][0]), 16, 0, 0);
      const int wn = lbn * 128 + r;
      const char* gpB = (const char*)(W + (size_t)wn * EE + k0) + ssrc;
      __builtin_amdgcn_global_load_lds(AS1C(gpB), AS3(&Bs[wid*32 + i*8][0]), 16, 0, 0);
    }
    __syncthreads();

    #pragma unroll
    for (int kc = 0; kc < 2; ++kc) {
      const int cc = kc * 64 + hi * 16;
      bf16x8 af[4], bfr[4];
      #pragma unroll
      for (int i = 0; i < 4; ++i) {
        const int ra = wr * 64 + i * 16 + lo;
        af[i]  = *(const bf16x8*)((const char*)&As[ra][0] + (cc ^ ((ra & 7) << 4)));
        const int rb = wc * 64 + i * 16 + lo;
        bfr[i] = *(const bf16x8*)((const char*)&Bs[rb][0] + (cc ^ ((rb & 7) << 4)));
      }
      __builtin_amdgcn_s_setprio(1);
      #pragma unroll
      for (int mi = 0; mi < 4; ++mi)
        #pragma unroll
        for (int ni = 0; ni < 4; ++ni)
          acc[mi][ni] = __builtin_amdgcn_mfma_f32_16x16x32_bf16(
              af[mi], bfr[ni], acc[mi][ni], 0, 0, 0);
      __builtin_amdgcn_s_setprio(0);
    }
  }

  float bv[4];
  #pragma unroll
  for (int ni = 0; ni < 4; ++ni)
    bv[ni] = bias[lbn * 128 + wc * 64 + ni * 16 + lo];

  #pragma unroll
  for (int mi = 0; mi < 4; ++mi) {
    #pragma unroll
    for (int r = 0; r < 4; ++r) {
      const int m = bm * 128 + wr * 64 + mi * 16 + hi * 4 + r;
      #pragma unroll
      for (int ni = 0; ni < 4; ++ni) {
        const int col = bn * 128 + wc * 64 + ni * 16 + lo;
        C[(size_t)m * nout + col] = __hip_bfloat16_raw{(unsigned short)pkbf(acc[mi][ni][r] + bv[ni])};
      }
    }
  }
}

// ---------------------------------------------------------------------------
// Fused out-proj: bid<1024 -> (A1,W1,b1)->C1 ; else (A2,W2,b2)->C2. NOUT=256.
// ---------------------------------------------------------------------------
__global__ __launch_bounds__(256,2) void gemm_oproj(
    const bf16* __restrict__ A1, const bf16* __restrict__ A2,
    const bf16* __restrict__ W1, const bf16* __restrict__ W2,
    const float* __restrict__ b1, const float* __restrict__ b2,
    bf16* __restrict__ C1, bf16* __restrict__ C2)
{
  __shared__ bf16 As[128][64];
  __shared__ bf16 Bs[128][64];
  const int bid = blockIdx.x;
  const int sel = bid >> 10;
  const int b2i = bid & 1023;
  const int xcd = b2i & 7;
  const int i0  = b2i >> 3;
  const int bm  = xcd * 64 + (i0 >> 1);
  const int bn  = i0 & 1;
  const bf16* A = sel ? A2 : A1;
  const bf16* W = sel ? W2 : W1;
  const float* bias = sel ? b2 : b1;
  bf16* C = sel ? C2 : C1;

  const int tid  = threadIdx.x;
  const int wid  = tid >> 6;
  const int lane = tid & 63;
  const int lo = lane & 15, hi = lane >> 4;
  const int wr = wid >> 1, wc = wid & 1;

  const int srow = lane >> 3;
  const int ssrc = ((lane & 7) << 4) ^ (srow << 4);

  f32x4 acc[4][4] = {};

  for (int k0 = 0; k0 < 256; k0 += 64) {
    __syncthreads();
    #pragma unroll
    for (int i = 0; i < 4; ++i) {
      const int r = wid * 32 + i * 8 + srow;
      const int m = bm * 128 + r;
      const char* gpA = (const char*)(A + (size_t)m * EE + k0) + ssrc;
      __builtin_amdgcn_global_load_lds(AS1C(gpA), AS3(&As[wid*32 + i*8][0]), 16, 0, 0);
      const int wn = bn * 128 + r;
      const char* gpB = (const char*)(W + (size_t)wn * EE + k0) + ssrc;
      __builtin_amdgcn_global_load_lds(AS1C(gpB), AS3(&Bs[wid*32 + i*8][0]), 16, 0, 0);
    }
    __syncthreads();

    #pragma unroll
    for (int kc = 0; kc < 2; ++kc) {
      const int cc = kc * 64 + hi * 16;
      bf16x8 af[4], bfr[4];
      #pragma unroll
      for (int i = 0; i < 4; ++i) {
        const int ra = wr * 64 + i * 16 + lo;
        af[i]  = *(const bf16x8*)((const char*)&As[ra][0] + (cc ^ ((ra & 7) << 4)));
        const int rb = wc * 64 + i * 16 + lo;
        bfr[i] = *(const bf16x8*)((const char*)&Bs[rb][0] + (cc ^ ((rb & 7) << 4)));
      }
      __builtin_amdgcn_s_setprio(1);
      #pragma unroll
      for (int mi = 0; mi < 4; ++mi)
        #pragma unroll
        for (int ni = 0; ni < 4; ++ni)
          acc[mi][ni] = __builtin_amdgcn_mfma_f32_16x16x32_bf16(
              af[mi], bfr[ni], acc[mi][ni], 0, 0, 0);
      __builtin_amdgcn_s_setprio(0);
    }
  }

  float bv[4];
  #pragma unroll
  for (int ni = 0; ni < 4; ++ni)
    bv[ni] = bias[bn * 128 + wc * 64 + ni * 16 + lo];

  #pragma unroll
  for (int mi = 0; mi < 4; ++mi) {
    #pragma unroll
    for (int r = 0; r < 4; ++r) {
      const int m = bm * 128 + wr * 64 + mi * 16 + hi * 4 + r;
      #pragma unroll
      for (int ni = 0; ni < 4; ++ni) {
        const int col = bn * 128 + wc * 64 + ni * 16 + lo;
        C[(size_t)m * EE + col] = __hip_bfloat16_raw{(unsigned short)pkbf(acc[mi][ni][r] + bv[ni])};
      }
    }
  }
}

// ---------------------------------------------------------------------------
// Fused axial attention. blocks [0,nrow): row attention; [nrow,..): col.
// Row: single-buffer LDS (Ks[64][72], Vt[64][72] = 18.4KB), async reg-stage,
//   swapped QK^T + in-register softmax + permuted-k PV.
// Col: VtC[4][64][36] (18.4KB, shared smem), Q/K frags direct from global.
// stride/base pointers runtime (fused: stride 1536; seq: 768).
// ---------------------------------------------------------------------------
__global__ __launch_bounds__(256,4) void attn_axial(
    const bf16* __restrict__ baseR, const bf16* __restrict__ baseC,
    const int stride, bf16* __restrict__ attnR, bf16* __restrict__ attnC,
    const int* __restrict__ sep_ptr, const int nrow)
{
  __shared__ bf16 smem[9216];
  const int tid  = threadIdx.x;
  const int lane = tid & 63;
  const int lo = lane & 15, hi = lane >> 4;

  if ((int)blockIdx.x < nrow) {
    // ================= row attention =================
    const int bid = blockIdx.x;
    const int xcd = bid & 7;
    const int idx = bid >> 3;
    const int pair = xcd * 64 + (idx >> 3);
    const int qt = idx & 7;
    const int t = pair >> 2;
    const int h = pair & 3;
    const int sep = *sep_ptr;
    const int wid = tid >> 6;
    bf16* Ks = smem;            // [64][72]
    bf16* Vt = smem + 4608;     // [64][72]

    const int qb = qt * 64;
    const int q0 = qb + wid * 16;

    bf16x8 qf[2];
    {
      const bf16* Qp = baseR + ((size_t)(q0 + lo) * DB + t) * stride + h * HDIM;
      bf16x8 a = *(const bf16x8*)(Qp + hi * 8);
      bf16x8 b = *(const bf16x8*)(Qp + 32 + hi * 8);
      #pragma unroll
      for (int j = 0; j < 8; ++j) {
        ((short*)&qf[0])[j] = pkbf(bf2f(((const bf16*)&a)[j]) * 0.125f);
        ((short*)&qf[1])[j] = pkbf(bf2f(((const bf16*)&b)[j]) * 0.125f);
      }
    }

    const int kr  = tid >> 2;
    const int kc4 = (tid & 3) * 16;
    const int vr  = tid & 63;
    const int vc  = (tid >> 6) * 16;
    const bf16* Kbase = baseR + ((size_t)kr * DB + t) * stride + EE + h * HDIM + kc4;
    const bf16* Vbase = baseR + ((size_t)vr * DB + t) * stride + 2*EE + h * HDIM + vc;
    const size_t kstep = (size_t)KBLK * DB * stride;

    f32x4 Oa[4] = {};
    float m_run = -1e30f, l_run = 0.f;

    const int nkt = (qb >= sep) ? ((sep + KBLK - 1) >> 6) : (NN >> 6);
    const bool need_mask = (qb + 64 > sep) && (nkt * KBLK > sep);

    bf16x8 kg0 = *(const bf16x8*)(Kbase);
    bf16x8 kg1 = *(const bf16x8*)(Kbase + 8);
    bf16x8 vg0 = *(const bf16x8*)(Vbase);
    bf16x8 vg1 = *(const bf16x8*)(Vbase + 8);

    for (int kt = 0; kt < nkt; ++kt) {
      const int k0 = kt * KBLK;

      // regs -> LDS (single buffer)
      *(bf16x8*)&Ks[kr*72 + kc4]     = kg0;
      *(bf16x8*)&Ks[kr*72 + kc4 + 8] = kg1;
      #pragma unroll
      for (int j = 0; j < 8; ++j) {
        Vt[(vc + j)*72 + vr]     = ((const bf16*)&vg0)[j];
        Vt[(vc + 8 + j)*72 + vr] = ((const bf16*)&vg1)[j];
      }
      __syncthreads();

      // issue next tile's loads (fly over compute)
      if (kt + 1 < nkt) {
        const size_t off = (size_t)(kt + 1) * kstep;
        kg0 = *(const bf16x8*)(Kbase + off);
        kg1 = *(const bf16x8*)(Kbase + off + 8);
        vg0 = *(const bf16x8*)(Vbase + off);
        vg1 = *(const bf16x8*)(Vbase + off + 8);
      }

      // S^T = K x Q^T : st[kb][r] = S[q=lo][k0 + kb*16 + 4*hi + r]
      f32x4 st[4];
      {
        bf16x8 kf[4][2];
        #pragma unroll
        for (int kb = 0; kb < 4; ++kb)
          #pragma unroll
          for (int kc = 0; kc < 2; ++kc)
            kf[kb][kc] = *(const bf16x8*)&Ks[(kb*16 + lo)*72 + kc*32 + hi*8];
        __builtin_amdgcn_s_setprio(1);
        #pragma unroll
        for (int kb = 0; kb < 4; ++kb) {
          st[kb] = (f32x4){0,0,0,0};
          #pragma unroll
          for (int kc = 0; kc < 2; ++kc)
            st[kb] = __builtin_amdgcn_mfma_f32_16x16x32_bf16(
                kf[kb][kc], qf[kc], st[kb], 0, 0, 0);
        }
        __builtin_amdgcn_s_setprio(0);
      }

      if (need_mask && k0 + KBLK > sep) {
        const int qq = q0 + lo;
        #pragma unroll
        for (int kb = 0; kb < 4; ++kb)
          #pragma unroll
          for (int r = 0; r < 4; ++r) {
            const int kk = k0 + kb*16 + 4*hi + r;
            if (qq >= sep && kk >= sep) st[kb][r] = -1e30f;
          }
      }

      float mx = -1e30f;
      #pragma unroll
      for (int kb = 0; kb < 4; ++kb)
        #pragma unroll
        for (int r = 0; r < 4; ++r) mx = fmaxf(mx, st[kb][r]);
      mx = fmaxf(mx, __shfl_xor(mx, 16));
      mx = fmaxf(mx, __shfl_xor(mx, 32));

      if (__any(mx - m_run > 5.f)) {
        const float mn = fmaxf(m_run, mx);
        const float corr = __expf(m_run - mn);
        m_run = mn;
        l_run *= corr;
        float c4[4];
        #pragma unroll
        for (int r = 0; r < 4; ++r) c4[r] = __shfl(corr, hi*4 + r);
        #pragma unroll
        for (int n = 0; n < 4; ++n)
          #pragma unroll
          for (int r = 0; r < 4; ++r) Oa[n][r] *= c4[r];
      }

      float s0 = 0.f;
      #pragma unroll
      for (int kb = 0; kb < 4; ++kb)
        #pragma unroll
        for (int r = 0; r < 4; ++r) {
          const float pv = __expf(st[kb][r] - m_run);
          st[kb][r] = pv;
          s0 += pv;
        }
      s0 += __shfl_xor(s0, 16);
      s0 += __shfl_xor(s0, 32);
      l_run += s0;

      // in-lane P repack
      bf16x8 pa[2];
      #pragma unroll
      for (int kc = 0; kc < 2; ++kc)
        #pragma unroll
        for (int j = 0; j < 8; ++j)
          ((short*)&pa[kc])[j] = pkbf(st[kc*2 + (j>>2)][j&3]);

      // PV with permuted-k V frags
      __builtin_amdgcn_s_setprio(1);
      #pragma unroll
      for (int n = 0; n < 4; ++n) {
        #pragma unroll
        for (int kc = 0; kc < 2; ++kc) {
          const bf16* vrow = &Vt[(n*16 + lo)*72];
          bf16x4 v0 = *(const bf16x4*)(vrow + kc*32 + 4*hi);
          bf16x4 v1 = *(const bf16x4*)(vrow + kc*32 + 16 + 4*hi);
          bf16x8 vf = __builtin_shufflevector(v0, v1, 0,1,2,3,4,5,6,7);
          Oa[n] = __builtin_amdgcn_mfma_f32_16x16x32_bf16(pa[kc], vf, Oa[n], 0, 0, 0);
        }
      }
      __builtin_amdgcn_s_setprio(0);
      __syncthreads();   // all LDS reads done before next tile's writes
    }

    float linv[4];
    #pragma unroll
    for (int r = 0; r < 4; ++r) linv[r] = 1.f / __shfl(l_run, hi*4 + r);
    #pragma unroll
    for (int r = 0; r < 4; ++r) {
      const int qq = q0 + hi*4 + r;
      bf16* Op = attnR + ((size_t)qq * DB + t) * EE + h * HDIM;
      #pragma unroll
      for (int n = 0; n < 4; ++n)
        Op[n*16 + lo] = __hip_bfloat16_raw{(unsigned short)pkbf(Oa[n][r] * linv[r])};
    }
  } else {
    // ================= col attention =================
    const int cb = blockIdx.x - nrow;   // n*4 + b
    const int n = cb >> 2;
    const int b = cb & 3;
    const int h = tid >> 6;             // wave = head

    // stage V^T into smem as [4][64][36]
    {
      const int k  = tid & 31;
      const int hh = tid >> 6;
      const int dh = ((tid >> 5) & 1) * 32;
      const bf16* Vp = baseC + ((size_t)(n*DB + k*4 + b)) * stride + 2*EE + hh*64 + dh;
      #pragma unroll
      for (int c = 0; c < 4; ++c) {
        bf16x8 vv = *(const bf16x8*)(Vp + c*8);
        #pragma unroll
        for (int j = 0; j < 8; ++j)
          smem[hh*2304 + (dh + c*8 + j)*36 + k] = ((const bf16*)&vv)[j];
      }
    }

    bf16x8 qf[2][2], kf[2][2];
    #pragma unroll
    for (int mt = 0; mt < 2; ++mt) {
      const bf16* Qp = baseC + ((size_t)(n*DB + (mt*16 + lo)*4 + b)) * stride + h*64;
      #pragma unroll
      for (int kc = 0; kc < 2; ++kc) {
        bf16x8 v = *(const bf16x8*)(Qp + kc*32 + hi*8);
        #pragma unroll
        for (int j = 0; j < 8; ++j)
          ((short*)&v)[j] = pkbf(bf2f(((const bf16*)&v)[j]) * 0.125f);
        qf[mt][kc] = v;
      }
      const bf16* Kp = Qp + EE;
      kf[mt][0] = *(const bf16x8*)(Kp + hi*8);
      kf[mt][1] = *(const bf16x8*)(Kp + 32 + hi*8);
    }
    __syncthreads();

    f32x4 st[2][2];
    #pragma unroll
    for (int kt = 0; kt < 2; ++kt)
      #pragma unroll
      for (int mt = 0; mt < 2; ++mt) {
        f32x4 a = {0,0,0,0};
        a = __builtin_amdgcn_mfma_f32_16x16x32_bf16(kf[kt][0], qf[mt][0], a, 0, 0, 0);
        a = __builtin_amdgcn_mfma_f32_16x16x32_bf16(kf[kt][1], qf[mt][1], a, 0, 0, 0);
        st[kt][mt] = a;
      }

    float l[2];
    #pragma unroll
    for (int mt = 0; mt < 2; ++mt) {
      float mx = -1e30f;
      #pragma unroll
      for (int kt = 0; kt < 2; ++kt)
        #pragma unroll
        for (int r = 0; r < 4; ++r) mx = fmaxf(mx, st[kt][mt][r]);
      mx = fmaxf(mx, __shfl_xor(mx, 16));
      mx = fmaxf(mx, __shfl_xor(mx, 32));
      float s0 = 0.f;
      #pragma unroll
      for (int kt = 0; kt < 2; ++kt)
        #pragma unroll
        for (int r = 0; r < 4; ++r) {
          const float pv = __expf(st[kt][mt][r] - mx);
          st[kt][mt][r] = pv;
          s0 += pv;
        }
      s0 += __shfl_xor(s0, 16);
      s0 += __shfl_xor(s0, 32);
      l[mt] = s0;
    }

    bf16x8 pa[2];
    #pragma unroll
    for (int mt = 0; mt < 2; ++mt)
      #pragma unroll
      for (int j = 0; j < 8; ++j)
        ((short*)&pa[mt])[j] = pkbf(st[j>>2][mt][j&3]);

    f32x4 Oa[2][4] = {};
    #pragma unroll
    for (int nn = 0; nn < 4; ++nn) {
      const bf16* vrow = &smem[h*2304 + (nn*16 + lo)*36];
      bf16x4 v0 = *(const bf16x4*)(vrow + 4*hi);
      bf16x4 v1 = *(const bf16x4*)(vrow + 16 + 4*hi);
      bf16x8 vf = __builtin_shufflevector(v0, v1, 0,1,2,3,4,5,6,7);
      Oa[0][nn] = __builtin_amdgcn_mfma_f32_16x16x32_bf16(pa[0], vf, Oa[0][nn], 0, 0, 0);
      Oa[1][nn] = __builtin_amdgcn_mfma_f32_16x16x32_bf16(pa[1], vf, Oa[1][nn], 0, 0, 0);
    }

    float linv[2][4];
    #pragma unroll
    for (int mt = 0; mt < 2; ++mt)
      #pragma unroll
      for (int r = 0; r < 4; ++r)
        linv[mt][r] = 1.f / __shfl(l[mt], hi*4 + r);
    #pragma unroll
    for (int mt = 0; mt < 2; ++mt) {
      #pragma unroll
      for (int r = 0; r < 4; ++r) {
        const int q = mt*16 + hi*4 + r;
        bf16* Op = attnC + ((size_t)(n*DB + q*4 + b)) * EE + h*64;
        #pragma unroll
        for (int nn = 0; nn < 4; ++nn)
          Op[nn*16 + lo] = __hip_bfloat16_raw{(unsigned short)pkbf(Oa[mt][nn][r] * linv[mt][r])};
      }
    }
  }
}

// ---------------------------------------------------------------------------
// Final: out = LayerNorm(src_f32 + r + c).  4 tokens/block, shuffle reduce.
// ---------------------------------------------------------------------------
__global__ __launch_bounds__(256) void ln_kernel(
    const float* __restrict__ src, const bf16* __restrict__ rp,
    const bf16* __restrict__ cp, const float* __restrict__ g,
    const float* __restrict__ b, float* __restrict__ out)
{
  const int m = blockIdx.x * 4 + (threadIdx.x >> 6);
  const int lane = threadIdx.x & 63;
  const float4 s4 = ((const float4*)src)[(size_t)m*64 + lane];
  const bf16x4 r4 = ((const bf16x4*)rp)[(size_t)m*64 + lane];
  const bf16x4 c4 = ((const bf16x4*)cp)[(size_t)m*64 + lane];
  float x[4];
  x[0] = s4.x + bf2f(((const bf16*)&r4)[0]) + bf2f(((const bf16*)&c4)[0]);
  x[1] = s4.y + bf2f(((const bf16*)&r4)[1]) + bf2f(((const bf16*)&c4)[1]);
  x[2] = s4.z + bf2f(((const bf16*)&r4)[2]) + bf2f(((const bf16*)&c4)[2]);
  x[3] = s4.w + bf2f(((const bf16*)&r4)[3]) + bf2f(((const bf16*)&c4)[3]);
  float sum = x[0] + x[1] + x[2] + x[3];
  #pragma unroll
  for (int off = 1; off < 64; off <<= 1) sum += __shfl_xor(sum, off);
  const float mu = sum * (1.f/EE);
  float d[4];
  #pragma unroll
  for (int j = 0; j < 4; ++j) d[j] = x[j] - mu;
  float ss = d[0]*d[0] + d[1]*d[1] + d[2]*d[2] + d[3]*d[3];
  #pragma unroll
  for (int off = 1; off < 64; off <<= 1) ss += __shfl_xor(ss, off);
  const float rstd = rsqrtf(ss * (1.f/EE) + 1e-5f);
  const float4 g4 = ((const float4*)g)[lane];
  const float4 b4 = ((const float4*)b)[lane];
  float4 o;
  o.x = d[0] * rstd * g4.x + b4.x;
  o.y = d[1] * rstd * g4.y + b4.y;
  o.z = d[2] * rstd * g4.z + b4.z;
  o.w = d[3] * rstd * g4.w + b4.w;
  ((float4*)out)[(size_t)m*64 + lane] = o;
}

// ---------------------------------------------------------------------------
extern "C" void kernel_launch(void* const* d_in, const int* in_sizes, int n_in,
                              void* d_out, int out_size, void* d_ws, size_t ws_size,
                              hipStream_t stream)
{
  const float* src      = (const float*)d_in[0];
  const float* w_in_row = (const float*)d_in[1];
  const float* b_in_row = (const float*)d_in[2];
  const float* w_out_row= (const float*)d_in[3];
  const float* b_out_row= (const float*)d_in[4];
  const float* w_in_col = (const float*)d_in[5];
  const float* b_in_col = (const float*)d_in[6];
  const float* w_out_col= (const float*)d_in[7];
  const float* b_out_col= (const float*)d_in[8];
  const float* ln_g     = (const float*)d_in[9];
  const float* ln_b     = (const float*)d_in[10];
  const int*   sep_ptr  = (const int*)d_in[12];
  float* out = (float*)d_out;

  char* ws = (char*)d_ws;
  dim3 blk(256);

  if (ws_size >= 268435456ULL) {
    // ---- fused layout (256 MiB) ----
    bf16* qkv    = (bf16*)(ws);               // [65536][1536]  192 MiB
    bf16* attnR  = (bf16*)(ws + 201326592);   // 32 MiB
    bf16* attnC  = (bf16*)(ws + 234881024);   // 32 MiB
    bf16* src_bf = attnR;                     // overlay (dead before attn)
    bf16* wir    = (bf16*)(ws + 234881024);   // overlay attnC (dead before attn)
    bf16* wic    = (bf16*)(ws + 235274240);
    bf16* wor    = (bf16*)(ws + 67108864);    // inside dead qkv (after attn)
    bf16* woc    = (bf16*)(ws + 67239936);
    bf16* r_out  = (bf16*)(ws);               // qkv dead after attn
    bf16* c_out  = (bf16*)(ws + 33554432);

    cvt_kernel<<<dim3(8192), blk, 0, stream>>>(src, src_bf, MTOK*EE);
    cvt_w_kernel<<<dim3(192), blk, 0, stream>>>(w_in_row, w_in_col, wir, wic);
    gemm_qkv<12><<<dim3(512*12), blk, 0, stream>>>(
        src_bf, wir, wic, b_in_row, b_in_col, qkv, 6, 1536);
    attn_axial<<<dim3(6144), blk, 0, stream>>>(
        qkv, qkv + 768, 1536, attnR, attnC, sep_ptr, 4096);
    cvt_w2_kernel<<<dim3(64), blk, 0, stream>>>(w_out_row, w_out_col, wor, woc);
    gemm_oproj<<<dim3(2048), blk, 0, stream>>>(
        attnR, attnC, wor, woc, b_out_row, b_out_col, r_out, c_out);
    ln_kernel<<<dim3(MTOK/4), blk, 0, stream>>>(src, r_out, c_out, ln_g, ln_b, out);
  } else {
    // ---- sequential layout (<= 193 MiB, proven-safe) ----
    bf16* qkv    = (bf16*)(ws);               // [65536][768]  96 MiB
    bf16* attnR  = (bf16*)(ws + 100663296);
    bf16* attnC  = (bf16*)(ws + 134217728);
    bf16* src_bf = (bf16*)(ws + 167772160);
    bf16* wir    = (bf16*)(ws + 201326592);
    bf16* wic    = (bf16*)(ws + 201719808);
    bf16* wor    = (bf16*)(ws + 67108864);    // inside dead qkv (after attn col)
    bf16* woc    = (bf16*)(ws + 67239936);
    bf16* r_out  = (bf16*)(ws);               // qkv dead after attn col
    bf16* c_out  = (bf16*)(ws + 33554432);

    cvt_kernel<<<dim3(8192), blk, 0, stream>>>(src, src_bf, MTOK*EE);
    cvt_w_kernel<<<dim3(192), blk, 0, stream>>>(w_in_row, w_in_col, wir, wic);
    gemm_qkv<6><<<dim3(512*6), blk, 0, stream>>>(
        src_bf, wir, wir, b_in_row, b_in_row, qkv, 6, 768);
    attn_axial<<<dim3(4096), blk, 0, stream>>>(
        qkv, qkv, 768, attnR, attnC, sep_ptr, 4096);
    gemm_qkv<6><<<dim3(512*6), blk, 0, stream>>>(
        src_bf, wic, wic, b_in_col, b_in_col, qkv, 6, 768);
    attn_axial<<<dim3(2048), blk, 0, stream>>>(
        qkv, qkv, 768, attnR, attnC, sep_ptr, 0);
    cvt_w2_kernel<<<dim3(64), blk, 0, stream>>>(w_out_row, w_out_col, wor, woc);
    gemm_oproj<<<dim3(2048), blk, 0, stream>>>(
        attnR, attnC, wor, woc, b_out_row, b_out_col, r_out, c_out);
    ln_kernel<<<dim3(MTOK/4), blk, 0, stream>>>(src, r_out, c_out, ln_g, ln_b, out);
  }
}